// Round 5
// baseline (384.558 us; speedup 1.0000x reference)
//
#include <hip/hip_runtime.h>

typedef unsigned short ushort_t;
typedef unsigned int u32;
typedef short short8 __attribute__((ext_vector_type(8)));
typedef float f32x4 __attribute__((ext_vector_type(4)));
typedef float f32x16 __attribute__((ext_vector_type(16)));

#define NTOK 4096
#define NCOLS 65536
#define CIN 256

__device__ __forceinline__ float b2f(ushort_t u) {
    union { unsigned int i; float f; } v; v.i = ((unsigned int)u) << 16; return v.f;
}
__device__ __forceinline__ ushort_t f2b(float f) {
    union { float f; unsigned int i; } v; v.f = f;
    unsigned int r = v.i + 0x7FFFu + ((v.i >> 16) & 1u);   // RNE
    return (ushort_t)(r >> 16);
}

__device__ __forceinline__ void gl_lds16(const ushort_t* g, ushort_t* l) {
    __builtin_amdgcn_global_load_lds(
        (const __attribute__((address_space(1))) u32*)(const void*)g,
        (__attribute__((address_space(3))) u32*)(void*)l,
        16, 0, 0);
}

// ---------------------------------------------------------------------------
// weights fp32 -> bf16; zero ctx accumulator (512 KB) in d_out
__global__ __launch_bounds__(256) void cvt_w(const float* __restrict__ wq,
                                             const float* __restrict__ wp,
                                             ushort_t* __restrict__ wqb,
                                             ushort_t* __restrict__ wpb,
                                             float* __restrict__ scz) {
    int i = blockIdx.x * 256 + threadIdx.x;      // 0 .. 262143
    if (i < 768 * 256) wqb[i] = f2b(wq[i]);
    else               wpb[i - 768 * 256] = f2b(wp[i - 768 * 256]);
    if (i < 131072) scz[i] = 0.f;
}

// ---------------------------------------------------------------------------
// x fp32 [16][256][4096] -> xt bf16 [65536][256], LDS-tiled (both sides coalesced)
__global__ __launch_bounds__(256) void transpose_x(const float* __restrict__ x,
                                                   ushort_t* __restrict__ xt) {
    __shared__ ushort_t lds[64 * 264];           // 33,792 B; 528B rows (16B-aligned)
    int tid = threadIdx.x;
    int g0 = blockIdx.x * 64;                    // 64 tokens per block
    int b = g0 >> 12, n0 = g0 & 4095;
    const float* src = x + (size_t)b * (CIN * NTOK);
    int tn = tid & 63, cg = tid >> 6;
    for (int c4 = 0; c4 < 64; c4++) {
        int c = c4 * 4 + cg;
        lds[tn * 264 + c] = f2b(src[(size_t)c * NTOK + n0 + tn]);
    }
    __syncthreads();
    int tok = tid >> 2, c8 = (tid & 3) * 8;
    ushort_t* dst = xt + (size_t)(g0 + tok) * CIN + c8;
#pragma unroll
    for (int j = 0; j < 8; j++)
        *(short8*)(dst + j * 32) = *(const short8*)&lds[tok * 264 + c8 + j * 32];
}

// ---------------------------------------------------------------------------
// W-in-registers GEMM: BM=256 x BN=128, 512 thr / 8 waves (4m x 2n quadrants,
// each wave 64 rows x 64 cols). W fragments afr[8][4] live in VGPRs (loaded
// once); LDS holds one full-K Xc panel (128 cols x 256 K = 64 KB). Per
// col-tile: ONE stage + ONE barrier-pair, then 8 K-steps of pure
// ds_read+MFMA (no mid-K barriers). 2 col-tiles per block.
// Fragment math / MFMA / epilogue identical to the R1-verified kernel.
// mode 0: out_b[m*65536 + col] bf16   |   mode 1: out_f[b][m][n] fp32
__global__ __launch_bounds__(512, 2) void gemmW(const ushort_t* __restrict__ W,
                                                const ushort_t* __restrict__ Xc,
                                                const float* __restrict__ gamma,
                                                const float* __restrict__ beta,
                                                const float* __restrict__ mean,
                                                const float* __restrict__ var,
                                                ushort_t* __restrict__ out_b,
                                                float* __restrict__ out_f, int mode) {
    __shared__ __align__(16) ushort_t lB[32768];     // 64 KB: [ks][col][k8] = ks*4096+col*32+k
    int tid = threadIdx.x;
    int wave = tid >> 6, lane = tid & 63;
    int l15 = lane & 15, q = lane >> 4;
    int mq = wave >> 1, nq = wave & 1;               // 4 m-quadrants x 2 n-halves
    int m0 = blockIdx.y * 256;
    int mrow = m0 + mq * 64;

    // W fragments -> registers, once per block (same per-lane layout as LDS path)
    short8 afr[8][4];
#pragma unroll
    for (int ks = 0; ks < 8; ks++)
#pragma unroll
        for (int i = 0; i < 4; i++)
            afr[ks][i] = *(const short8*)(W + (size_t)(mrow + i * 16 + l15) * CIN
                                            + ks * 32 + q * 8);

    const ushort_t* gB = Xc + (size_t)(blockIdx.x * 256 + (tid >> 2)) * CIN
                            + (tid & 3) * 8;

    for (int ct = 0; ct < 2; ct++) {
        if (ct) __builtin_amdgcn_s_barrier();        // all waves done reading lB
        const ushort_t* gBt = gB + ct * 128 * CIN;   // this tile's 128 cols
#pragma unroll
        for (int ks = 0; ks < 8; ks++)
            gl_lds16(gBt + ks * 32, &lB[ks * 4096 + tid * 8]);
        asm volatile("s_waitcnt vmcnt(0)" ::: "memory");
        __builtin_amdgcn_s_barrier();                // tile staged by all waves

        f32x4 acc[4][4];
#pragma unroll
        for (int i = 0; i < 4; i++)
#pragma unroll
            for (int j = 0; j < 4; j++)
#pragma unroll
                for (int r = 0; r < 4; r++) acc[i][j][r] = 0.f;

#pragma unroll
        for (int ks = 0; ks < 8; ks++) {
            short8 bf[4];
#pragma unroll
            for (int nj = 0; nj < 4; nj++)
                bf[nj] = *(const short8*)&lB[ks * 4096
                                             + (nq * 64 + nj * 16 + l15) * 32 + q * 8];
#pragma unroll
            for (int i = 0; i < 4; i++)
#pragma unroll
                for (int nj = 0; nj < 4; nj++)
                    acc[i][nj] = __builtin_amdgcn_mfma_f32_16x16x32_bf16(
                        afr[ks][i], bf[nj], acc[i][nj], 0, 0, 0);
        }

        int colb = blockIdx.x * 256 + ct * 128;
#pragma unroll
        for (int i = 0; i < 4; i++) {
#pragma unroll
            for (int r = 0; r < 4; r++) {
                int m = mrow + i * 16 + q * 4 + r;
                float sc = gamma[m] * rsqrtf(var[m] + 1e-5f);
                float sh = beta[m] - mean[m] * sc;
#pragma unroll
                for (int nj = 0; nj < 4; nj++) {
                    float val = acc[i][nj][r] * sc + sh;
                    int col = colb + nq * 64 + nj * 16 + l15;
                    if (mode == 0) {
                        out_b[(size_t)m * NCOLS + col] = f2b(val);
                    } else {
                        int bb = col >> 12, n = col & 4095;
                        out_f[(size_t)bb * (CIN * NTOK) + (size_t)m * NTOK + n] = val;
                    }
                }
            }
        }
    }
}

// ---------------------------------------------------------------------------
// S_q[c][b] = sum_n exp(q_raw[c][b*4096+n])   (one wave per (c,b) row)
__global__ __launch_bounds__(256) void qsum_ker(const ushort_t* __restrict__ qkv,
                                                float* __restrict__ qsums) {
    int tid = threadIdx.x, wave = tid >> 6, lane = tid & 63;
    int rid = blockIdx.x * 4 + wave;             // 0..4095
    int c = rid >> 4, b = rid & 15;
    const ushort_t* row = qkv + (size_t)c * NCOLS + b * NTOK;
    float s = 0.f;
#pragma unroll
    for (int j = 0; j < 8; j++) {
        short8 pk = *(const short8*)(row + j * 512 + lane * 8);
#pragma unroll
        for (int i = 0; i < 8; i++) s += __expf(b2f((ushort_t)pk[i]));
    }
    for (int off = 1; off < 64; off <<= 1) s += __shfl_xor(s, off);
    if (lane == 0) qsums[c * 16 + b] = s;
}

// ---------------------------------------------------------------------------
// ctx[bh][d][e] += sum_n ksm[d][n]*v[e][n]; k-softmax fused (d = lane dim l31)
__global__ __launch_bounds__(256) void ctx_ker(const ushort_t* __restrict__ qkv,
                                               float* __restrict__ ctxbuf) {
    int sl = blockIdx.x, bh = blockIdx.y;
    int b = bh >> 3, h = bh & 7;
    int tid = threadIdx.x, wave = tid >> 6, lane = tid & 63;
    int l31 = lane & 31, l5 = lane >> 5;
    int col0 = b * NTOK + sl * 512 + wave * 128;
    const ushort_t* krow = qkv + (size_t)(256 + h * 32 + l31) * NCOLS + col0 + l5 * 8;
    const ushort_t* vrow = qkv + (size_t)(512 + h * 32 + l31) * NCOLS + col0 + l5 * 8;
    f32x16 acc;
#pragma unroll
    for (int i = 0; i < 16; i++) acc[i] = 0.f;
#pragma unroll
    for (int st = 0; st < 8; st++) {
        short8 kf = *(const short8*)(krow + st * 16);
        short8 vf = *(const short8*)(vrow + st * 16);   // v raw (B operand)
        short8 af;
#pragma unroll
        for (int j = 0; j < 8; j++) {
            float e = __expf(b2f((ushort_t)kf[j]));
            float t = e;
            t += __shfl_xor(t, 1);
            t += __shfl_xor(t, 2);
            t += __shfl_xor(t, 4);
            t += __shfl_xor(t, 8);
            t += __shfl_xor(t, 16);                     // sum over d (l31 group)
            af[j] = (short)f2b(__fdividef(e, t));
        }
        acc = __builtin_amdgcn_mfma_f32_32x32x16_bf16(af, vf, acc, 0, 0, 0);
    }
    __shared__ float red[4][1024];
#pragma unroll
    for (int r = 0; r < 16; r++) {
        int d = (r & 3) + 8 * (r >> 2) + 4 * l5;        // C/D row (m74/m101)
        red[wave][d * 32 + l31] = acc[r];
    }
    __syncthreads();
    int i0 = tid * 4;
#pragma unroll
    for (int i = 0; i < 4; i++) {
        int idx = i0 + i;
        float v = red[0][idx] + red[1][idx] + red[2][idx] + red[3][idx];
        atomicAdd(ctxbuf + (size_t)bh * 1024 + idx, v);
    }
}

// ---------------------------------------------------------------------------
// out[e][n] = sum_d ctx[d][e] * (exp(q[d][n])/S_q[d])  -> attT[token][256]
__global__ __launch_bounds__(256) void out_ker(const ushort_t* __restrict__ qkv,
                                               const float* __restrict__ ctxbuf,
                                               const float* __restrict__ qsums,
                                               ushort_t* __restrict__ attT) {
    int sl = blockIdx.x, bh = blockIdx.y;
    int b = bh >> 3, h = bh & 7;
    int tid = threadIdx.x, wave = tid >> 6, lane = tid & 63;
    int l31 = lane & 31, l5 = lane >> 5;
    __shared__ __align__(16) ushort_t ctxT[32 * 40];
    __shared__ __align__(16) ushort_t qT[256 * 40];
    __shared__ __align__(16) ushort_t obuf[4][32 * 40];

#pragma unroll
    for (int i = 0; i < 4; i++) {
        int idx = tid * 4 + i;
        int d = idx >> 5, e = idx & 31;
        ctxT[e * 40 + d] = f2b(ctxbuf[(size_t)bh * 1024 + idx]);  // k-norm already in ctx
    }
    __syncthreads();
    short8 a0 = *(const short8*)(ctxT + l31 * 40 + l5 * 8);
    short8 a1 = *(const short8*)(ctxT + l31 * 40 + 16 + l5 * 8);

    const ushort_t* qbase = qkv + (size_t)(h * 32) * NCOLS;
    int segbase = b * NTOK + sl * 512;
    int d = tid & 31, t8 = (tid >> 5) * 8;
    float sq = 1.f / qsums[(h * 32 + d) * 16 + b];     // per-thread row scale

    for (int nc = 0; nc < 2; nc++) {
        int gcol0 = segbase + nc * 256;
#pragma unroll
        for (int jj = 0; jj < 4; jj++) {
            int tok8 = jj * 64 + t8;
            short8 pk = *(const short8*)(qbase + (size_t)d * NCOLS + gcol0 + tok8);
#pragma unroll
            for (int j = 0; j < 8; j++)
                qT[(tok8 + j) * 40 + d] = f2b(__expf(b2f((ushort_t)pk[j])) * sq);
        }
        __syncthreads();
#pragma unroll
        for (int ti = 0; ti < 2; ti++) {
            int tok0 = (wave + ti * 4) * 32;
            f32x16 acc;
#pragma unroll
            for (int i = 0; i < 16; i++) acc[i] = 0.f;
            short8 b0 = *(const short8*)(qT + (size_t)(tok0 + l31) * 40 + l5 * 8);
            short8 b1 = *(const short8*)(qT + (size_t)(tok0 + l31) * 40 + 16 + l5 * 8);
            acc = __builtin_amdgcn_mfma_f32_32x32x16_bf16(a0, b0, acc, 0, 0, 0);
            acc = __builtin_amdgcn_mfma_f32_32x32x16_bf16(a1, b1, acc, 0, 0, 0);
#pragma unroll
            for (int r = 0; r < 16; r++) {
                int e = (r & 3) + 8 * (r >> 2) + 4 * l5;
                obuf[wave][l31 * 40 + e] = f2b(acc[r]);
            }
            __syncthreads();
            {
                int tok = lane >> 1, half = lane & 1;
                const ushort_t* srcp = &obuf[wave][tok * 40 + half * 16];
                short8 r0 = *(const short8*)srcp;
                short8 r1 = *(const short8*)(srcp + 8);
                size_t g = (size_t)(gcol0 + tok0 + tok) * 256 + h * 32 + half * 16;
                *(short8*)(attT + g) = r0;
                *(short8*)(attT + g + 8) = r1;
            }
            __syncthreads();
        }
        __syncthreads();
    }
}

// ---------------------------------------------------------------------------
extern "C" void kernel_launch(void* const* d_in, const int* in_sizes, int n_in,
                              void* d_out, int out_size, void* d_ws, size_t ws_size,
                              hipStream_t stream) {
    const float* x          = (const float*)d_in[0];
    const float* qkv_w      = (const float*)d_in[1];
    const float* qkv_gamma  = (const float*)d_in[2];
    const float* qkv_beta   = (const float*)d_in[3];
    const float* qkv_mean   = (const float*)d_in[4];
    const float* qkv_var    = (const float*)d_in[5];
    const float* proj_w     = (const float*)d_in[6];
    const float* proj_gamma = (const float*)d_in[7];
    const float* proj_beta  = (const float*)d_in[8];
    const float* proj_mean  = (const float*)d_in[9];
    const float* proj_var   = (const float*)d_in[10];

    ushort_t* wqb = (ushort_t*)d_ws;                 // 393,216 B
    ushort_t* wpb = wqb + 768 * 256;                 // 131,072 B
    ushort_t* xt  = wpb + 256 * 256;                 // 33.5 MB (also attT later)
    ushort_t* qkv = xt + (size_t)NCOLS * CIN;        // 100.7 MB
    float* out    = (float*)d_out;
    float* ctxbuf = (float*)d_out;                   // 512 KB scratch in d_out
    float* qsums  = ctxbuf + 131072;                 // 16 KB scratch in d_out

    cvt_w<<<1024, 256, 0, stream>>>(qkv_w, proj_w, wqb, wpb, ctxbuf);
    transpose_x<<<1024, 256, 0, stream>>>(x, xt);
    gemmW<<<dim3(256, 3), 512, 0, stream>>>(wqb, xt, qkv_gamma, qkv_beta,
                                            qkv_mean, qkv_var, qkv, nullptr, 0);
    qsum_ker<<<1024, 256, 0, stream>>>(qkv, qsums);
    ctx_ker<<<dim3(8, 128), 256, 0, stream>>>(qkv, ctxbuf);
    out_ker<<<dim3(8, 128), 256, 0, stream>>>(qkv, ctxbuf, qsums, xt);
    gemmW<<<dim3(256, 1), 512, 0, stream>>>(wpb, xt, proj_gamma, proj_beta,
                                            proj_mean, proj_var, nullptr, out, 1);
}

// Round 6
// 356.101 us; speedup vs baseline: 1.0799x; 1.0799x over previous
//
#include <hip/hip_runtime.h>

typedef unsigned short ushort_t;
typedef unsigned int u32;
typedef short short8 __attribute__((ext_vector_type(8)));
typedef float f32x4 __attribute__((ext_vector_type(4)));
typedef float f32x16 __attribute__((ext_vector_type(16)));

#define NTOK 4096
#define NCOLS 65536
#define CIN 256

__device__ __forceinline__ float b2f(ushort_t u) {
    union { unsigned int i; float f; } v; v.i = ((unsigned int)u) << 16; return v.f;
}
__device__ __forceinline__ ushort_t f2b(float f) {
    union { float f; unsigned int i; } v; v.f = f;
    unsigned int r = v.i + 0x7FFFu + ((v.i >> 16) & 1u);   // RNE
    return (ushort_t)(r >> 16);
}

__device__ __forceinline__ void gl_lds16(const ushort_t* g, ushort_t* l) {
    __builtin_amdgcn_global_load_lds(
        (const __attribute__((address_space(1))) u32*)(const void*)g,
        (__attribute__((address_space(3))) u32*)(void*)l,
        16, 0, 0);
}

// ---------------------------------------------------------------------------
// prep: x fp32 [16][256][4096] -> xt bf16 [65536][256]  (LDS-tiled transpose)
//       + weights fp32->bf16 + zero ctx/qsums scratch (folded cvt_w)
__global__ __launch_bounds__(256) void prep_x(const float* __restrict__ x,
                                              ushort_t* __restrict__ xt,
                                              const float* __restrict__ wq,
                                              const float* __restrict__ wp,
                                              ushort_t* __restrict__ wqb,
                                              ushort_t* __restrict__ wpb,
                                              float* __restrict__ scz) {
    __shared__ ushort_t lds[64 * 264];           // 33,792 B; 528B rows (16B-aligned)
    int tid = threadIdx.x;

    // folded cvt_w: 1 weight elem + 1 scratch-zero per thread
    int i = blockIdx.x * 256 + tid;              // 0 .. 262143
    if (i < 768 * 256) wqb[i] = f2b(wq[i]);
    else               wpb[i - 768 * 256] = f2b(wp[i - 768 * 256]);
    if (i < 135168) scz[i] = 0.f;                // ctxbuf (131072) + qsums (4096)

    int g0 = blockIdx.x * 64;                    // 64 tokens per block
    int b = g0 >> 12, n0 = g0 & 4095;
    const float* src = x + (size_t)b * (CIN * NTOK);
    int tn = tid & 63, cg = tid >> 6;
    for (int c4 = 0; c4 < 64; c4++) {
        int c = c4 * 4 + cg;
        lds[tn * 264 + c] = f2b(src[(size_t)c * NTOK + n0 + tn]);
    }
    __syncthreads();
    int tok = tid >> 2, c8 = (tid & 3) * 8;
    ushort_t* dst = xt + (size_t)(g0 + tok) * CIN + c8;
#pragma unroll
    for (int j = 0; j < 8; j++)
        *(short8*)(dst + j * 32) = *(const short8*)&lds[tok * 264 + c8 + j * 32];
}

// ---------------------------------------------------------------------------
// R1-proven 128x128-tile GEMM + BN epilogue. mode 0 additionally accumulates
// the q-softmax denominators (rows m<256): per-lane sum of exp over its 4
// cols -> shfl-reduce over l15 group -> one atomicAdd per (m,b) per wave.
// Semantics identical to the old qsum_ker (exp of the bf16-rounded value).
// mode 0: out_b[m*65536 + col] bf16   |   mode 1: out_f[b][m][n] fp32
__global__ __launch_bounds__(256) void gemm128(const ushort_t* __restrict__ W,
                                               const ushort_t* __restrict__ Xc,
                                               const float* __restrict__ gamma,
                                               const float* __restrict__ beta,
                                               const float* __restrict__ mean,
                                               const float* __restrict__ var,
                                               ushort_t* __restrict__ out_b,
                                               float* __restrict__ out_f,
                                               float* __restrict__ qsums, int mode) {
    __shared__ __align__(16) ushort_t lA[128 * 32];
    __shared__ __align__(16) ushort_t lB[128 * 32];
    int tid = threadIdx.x;
    int wave = tid >> 6, lane = tid & 63;
    int l15 = lane & 15, q = lane >> 4;
    int mh = wave >> 1, nh = wave & 1;
    int m0 = blockIdx.y * 128, colb = blockIdx.x * 128;

    f32x4 acc[4][4];
#pragma unroll
    for (int i = 0; i < 4; i++)
#pragma unroll
        for (int j = 0; j < 4; j++)
#pragma unroll
            for (int r = 0; r < 4; r++) acc[i][j][r] = 0.f;

    const ushort_t* gA0 = W  + (size_t)(m0 +      (tid >> 2)) * CIN + (tid & 3) * 8;
    const ushort_t* gA1 = W  + (size_t)(m0 + 64 + (tid >> 2)) * CIN + (tid & 3) * 8;
    const ushort_t* gB0 = Xc + (size_t)(colb +      (tid >> 2)) * CIN + (tid & 3) * 8;
    const ushort_t* gB1 = Xc + (size_t)(colb + 64 + (tid >> 2)) * CIN + (tid & 3) * 8;
    ushort_t* la0 = &lA[tid * 8];
    ushort_t* la1 = &lA[2048 + tid * 8];
    ushort_t* lb0 = &lB[tid * 8];
    ushort_t* lb1 = &lB[2048 + tid * 8];

    for (int k0 = 0; k0 < CIN; k0 += 32) {
        gl_lds16(gA0 + k0, la0);
        gl_lds16(gA1 + k0, la1);
        gl_lds16(gB0 + k0, lb0);
        gl_lds16(gB1 + k0, lb1);
        __syncthreads();
        short8 af[4], bf[4];
#pragma unroll
        for (int i = 0; i < 4; i++) {
            af[i] = *(const short8*)&lA[(mh * 64 + i * 16 + l15) * 32 + q * 8];
            bf[i] = *(const short8*)&lB[(nh * 64 + i * 16 + l15) * 32 + q * 8];
        }
#pragma unroll
        for (int mi = 0; mi < 4; mi++)
#pragma unroll
            for (int ni = 0; ni < 4; ni++)
                acc[mi][ni] = __builtin_amdgcn_mfma_f32_16x16x32_bf16(af[mi], bf[ni],
                                                                      acc[mi][ni], 0, 0, 0);
        __syncthreads();
    }

    int col_l = colb + nh * 64 + l15;
    int bq = colb >> 12;                          // batch of this col-tile (aligned)
#pragma unroll
    for (int mi = 0; mi < 4; mi++) {
#pragma unroll
        for (int r = 0; r < 4; r++) {
            int m = m0 + mh * 64 + mi * 16 + q * 4 + r;
            float sc = gamma[m] * rsqrtf(var[m] + 1e-5f);
            float sh = beta[m] - mean[m] * sc;
            float qs = 0.f;
#pragma unroll
            for (int ni = 0; ni < 4; ni++) {
                float val = acc[mi][ni][r] * sc + sh;
                int col = col_l + ni * 16;
                if (mode == 0) {
                    ushort_t bv = f2b(val);
                    out_b[(size_t)m * NCOLS + col] = bv;
                    if (m < 256) qs += __expf(b2f(bv));   // q rows: denom partial
                } else {
                    int bb = col >> 12, n = col & 4095;
                    out_f[(size_t)bb * (CIN * NTOK) + (size_t)m * NTOK + n] = val;
                }
            }
            if (mode == 0 && m < 256) {           // wave-uniform branch (m0,mi,r fixed)
                qs += __shfl_xor(qs, 1);
                qs += __shfl_xor(qs, 2);
                qs += __shfl_xor(qs, 4);
                qs += __shfl_xor(qs, 8);          // sum over 16 l15 lanes
                if (l15 == 0) atomicAdd(&qsums[m * 16 + bq], qs);
            }
        }
    }
}

// ---------------------------------------------------------------------------
// ctx[bh][d][e] += sum_n ksm[d][n]*v[e][n]; k-softmax fused (d = lane dim l31)
__global__ __launch_bounds__(256) void ctx_ker(const ushort_t* __restrict__ qkv,
                                               float* __restrict__ ctxbuf) {
    int sl = blockIdx.x, bh = blockIdx.y;
    int b = bh >> 3, h = bh & 7;
    int tid = threadIdx.x, wave = tid >> 6, lane = tid & 63;
    int l31 = lane & 31, l5 = lane >> 5;
    int col0 = b * NTOK + sl * 512 + wave * 128;
    const ushort_t* krow = qkv + (size_t)(256 + h * 32 + l31) * NCOLS + col0 + l5 * 8;
    const ushort_t* vrow = qkv + (size_t)(512 + h * 32 + l31) * NCOLS + col0 + l5 * 8;
    f32x16 acc;
#pragma unroll
    for (int i = 0; i < 16; i++) acc[i] = 0.f;
#pragma unroll
    for (int st = 0; st < 8; st++) {
        short8 kf = *(const short8*)(krow + st * 16);
        short8 vf = *(const short8*)(vrow + st * 16);   // v raw (B operand)
        short8 af;
#pragma unroll
        for (int j = 0; j < 8; j++) {
            float e = __expf(b2f((ushort_t)kf[j]));
            float t = e;
            t += __shfl_xor(t, 1);
            t += __shfl_xor(t, 2);
            t += __shfl_xor(t, 4);
            t += __shfl_xor(t, 8);
            t += __shfl_xor(t, 16);                     // sum over d (l31 group)
            af[j] = (short)f2b(__fdividef(e, t));
        }
        acc = __builtin_amdgcn_mfma_f32_32x32x16_bf16(af, vf, acc, 0, 0, 0);
    }
    __shared__ float red[4][1024];
#pragma unroll
    for (int r = 0; r < 16; r++) {
        int d = (r & 3) + 8 * (r >> 2) + 4 * l5;        // C/D row (m74/m101)
        red[wave][d * 32 + l31] = acc[r];
    }
    __syncthreads();
    int i0 = tid * 4;
#pragma unroll
    for (int i = 0; i < 4; i++) {
        int idx = i0 + i;
        float v = red[0][idx] + red[1][idx] + red[2][idx] + red[3][idx];
        atomicAdd(ctxbuf + (size_t)bh * 1024 + idx, v);
    }
}

// ---------------------------------------------------------------------------
// out[e][n] = sum_d ctx[d][e] * (exp(q[d][n])/S_q[d])  -> attT[token][256]
__global__ __launch_bounds__(256) void out_ker(const ushort_t* __restrict__ qkv,
                                               const float* __restrict__ ctxbuf,
                                               const float* __restrict__ qsums,
                                               ushort_t* __restrict__ attT) {
    int sl = blockIdx.x, bh = blockIdx.y;
    int b = bh >> 3, h = bh & 7;
    int tid = threadIdx.x, wave = tid >> 6, lane = tid & 63;
    int l31 = lane & 31, l5 = lane >> 5;
    __shared__ __align__(16) ushort_t ctxT[32 * 40];
    __shared__ __align__(16) ushort_t qT[256 * 40];
    __shared__ __align__(16) ushort_t obuf[4][32 * 40];

#pragma unroll
    for (int i = 0; i < 4; i++) {
        int idx = tid * 4 + i;
        int d = idx >> 5, e = idx & 31;
        ctxT[e * 40 + d] = f2b(ctxbuf[(size_t)bh * 1024 + idx]);  // k-norm already in ctx
    }
    __syncthreads();
    short8 a0 = *(const short8*)(ctxT + l31 * 40 + l5 * 8);
    short8 a1 = *(const short8*)(ctxT + l31 * 40 + 16 + l5 * 8);

    const ushort_t* qbase = qkv + (size_t)(h * 32) * NCOLS;
    int segbase = b * NTOK + sl * 512;
    int d = tid & 31, t8 = (tid >> 5) * 8;
    float sq = 1.f / qsums[(h * 32 + d) * 16 + b];     // per-thread row scale

    for (int nc = 0; nc < 2; nc++) {
        int gcol0 = segbase + nc * 256;
#pragma unroll
        for (int jj = 0; jj < 4; jj++) {
            int tok8 = jj * 64 + t8;
            short8 pk = *(const short8*)(qbase + (size_t)d * NCOLS + gcol0 + tok8);
#pragma unroll
            for (int j = 0; j < 8; j++)
                qT[(tok8 + j) * 40 + d] = f2b(__expf(b2f((ushort_t)pk[j])) * sq);
        }
        __syncthreads();
#pragma unroll
        for (int ti = 0; ti < 2; ti++) {
            int tok0 = (wave + ti * 4) * 32;
            f32x16 acc;
#pragma unroll
            for (int i = 0; i < 16; i++) acc[i] = 0.f;
            short8 b0 = *(const short8*)(qT + (size_t)(tok0 + l31) * 40 + l5 * 8);
            short8 b1 = *(const short8*)(qT + (size_t)(tok0 + l31) * 40 + 16 + l5 * 8);
            acc = __builtin_amdgcn_mfma_f32_32x32x16_bf16(a0, b0, acc, 0, 0, 0);
            acc = __builtin_amdgcn_mfma_f32_32x32x16_bf16(a1, b1, acc, 0, 0, 0);
#pragma unroll
            for (int r = 0; r < 16; r++) {
                int e = (r & 3) + 8 * (r >> 2) + 4 * l5;
                obuf[wave][l31 * 40 + e] = f2b(acc[r]);
            }
            __syncthreads();
            {
                int tok = lane >> 1, half = lane & 1;
                const ushort_t* srcp = &obuf[wave][tok * 40 + half * 16];
                short8 r0 = *(const short8*)srcp;
                short8 r1 = *(const short8*)(srcp + 8);
                size_t g = (size_t)(gcol0 + tok0 + tok) * 256 + h * 32 + half * 16;
                *(short8*)(attT + g) = r0;
                *(short8*)(attT + g + 8) = r1;
            }
            __syncthreads();
        }
        __syncthreads();
    }
}

// ---------------------------------------------------------------------------
extern "C" void kernel_launch(void* const* d_in, const int* in_sizes, int n_in,
                              void* d_out, int out_size, void* d_ws, size_t ws_size,
                              hipStream_t stream) {
    const float* x          = (const float*)d_in[0];
    const float* qkv_w      = (const float*)d_in[1];
    const float* qkv_gamma  = (const float*)d_in[2];
    const float* qkv_beta   = (const float*)d_in[3];
    const float* qkv_mean   = (const float*)d_in[4];
    const float* qkv_var    = (const float*)d_in[5];
    const float* proj_w     = (const float*)d_in[6];
    const float* proj_gamma = (const float*)d_in[7];
    const float* proj_beta  = (const float*)d_in[8];
    const float* proj_mean  = (const float*)d_in[9];
    const float* proj_var   = (const float*)d_in[10];

    ushort_t* wqb = (ushort_t*)d_ws;                 // 393,216 B
    ushort_t* wpb = wqb + 768 * 256;                 // 131,072 B
    ushort_t* xt  = wpb + 256 * 256;                 // 33.5 MB (also attT later)
    ushort_t* qkv = xt + (size_t)NCOLS * CIN;        // 100.7 MB
    float* out    = (float*)d_out;
    float* ctxbuf = (float*)d_out;                   // 512 KB scratch in d_out
    float* qsums  = ctxbuf + 131072;                 // 16 KB scratch in d_out

    prep_x<<<1024, 256, 0, stream>>>(x, xt, qkv_w, proj_w, wqb, wpb, ctxbuf);
    gemm128<<<dim3(512, 6), 256, 0, stream>>>(wqb, xt, qkv_gamma, qkv_beta,
                                              qkv_mean, qkv_var, qkv, nullptr,
                                              qsums, 0);
    ctx_ker<<<dim3(8, 128), 256, 0, stream>>>(qkv, ctxbuf);
    out_ker<<<dim3(8, 128), 256, 0, stream>>>(qkv, ctxbuf, qsums, xt);
    gemm128<<<dim3(512, 2), 256, 0, stream>>>(wpb, xt, proj_gamma, proj_beta,
                                              proj_mean, proj_var, nullptr, out,
                                              nullptr, 1);
}

// Round 7
// 292.238 us; speedup vs baseline: 1.3159x; 1.2185x over previous
//
#include <hip/hip_runtime.h>

typedef unsigned short ushort_t;
typedef unsigned int u32;
typedef short short8 __attribute__((ext_vector_type(8)));
typedef float f32x4 __attribute__((ext_vector_type(4)));
typedef float f32x16 __attribute__((ext_vector_type(16)));

#define NTOK 4096
#define NCOLS 65536
#define CIN 256

__device__ __forceinline__ float b2f(ushort_t u) {
    union { unsigned int i; float f; } v; v.i = ((unsigned int)u) << 16; return v.f;
}
__device__ __forceinline__ ushort_t f2b(float f) {
    union { float f; unsigned int i; } v; v.f = f;
    unsigned int r = v.i + 0x7FFFu + ((v.i >> 16) & 1u);   // RNE
    return (ushort_t)(r >> 16);
}

__device__ __forceinline__ void gl_lds16(const ushort_t* g, ushort_t* l) {
    __builtin_amdgcn_global_load_lds(
        (const __attribute__((address_space(1))) u32*)(const void*)g,
        (__attribute__((address_space(3))) u32*)(void*)l,
        16, 0, 0);
}

// ---------------------------------------------------------------------------
// prep: x fp32 [16][256][4096] -> xt bf16 [65536][256]  (LDS-tiled transpose)
//       + weights fp32->bf16 (folded cvt_w; no scratch zeroing needed — all
//       scratch buffers are fully written by their producers, no atomics)
__global__ __launch_bounds__(256) void prep_x(const float* __restrict__ x,
                                              ushort_t* __restrict__ xt,
                                              const float* __restrict__ wq,
                                              const float* __restrict__ wp,
                                              ushort_t* __restrict__ wqb,
                                              ushort_t* __restrict__ wpb) {
    __shared__ ushort_t lds[64 * 264];           // 33,792 B; 528B rows (16B-aligned)
    int tid = threadIdx.x;

    // folded cvt_w: 1 weight elem per thread
    int i = blockIdx.x * 256 + tid;              // 0 .. 262143
    if (i < 768 * 256) wqb[i] = f2b(wq[i]);
    else               wpb[i - 768 * 256] = f2b(wp[i - 768 * 256]);

    int g0 = blockIdx.x * 64;                    // 64 tokens per block
    int b = g0 >> 12, n0 = g0 & 4095;
    const float* src = x + (size_t)b * (CIN * NTOK);
    int tn = tid & 63, cg = tid >> 6;
    for (int c4 = 0; c4 < 64; c4++) {
        int c = c4 * 4 + cg;
        lds[tn * 264 + c] = f2b(src[(size_t)c * NTOK + n0 + tn]);
    }
    __syncthreads();
    int tok = tid >> 2, c8 = (tid & 3) * 8;
    ushort_t* dst = xt + (size_t)(g0 + tok) * CIN + c8;
#pragma unroll
    for (int j = 0; j < 8; j++)
        *(short8*)(dst + j * 32) = *(const short8*)&lds[tok * 264 + c8 + j * 32];
}

// ---------------------------------------------------------------------------
// R1-proven 128x128-tile GEMM + thin BN epilogue (R6 lesson: NOTHING else in
// the epilogue — the qsum/atomic fold cost +54 µs via RMW traffic).
// mode 0: out_b[m*65536 + col] bf16   |   mode 1: out_f[b][m][n] fp32
__global__ __launch_bounds__(256) void gemm128(const ushort_t* __restrict__ W,
                                               const ushort_t* __restrict__ Xc,
                                               const float* __restrict__ gamma,
                                               const float* __restrict__ beta,
                                               const float* __restrict__ mean,
                                               const float* __restrict__ var,
                                               ushort_t* __restrict__ out_b,
                                               float* __restrict__ out_f, int mode) {
    __shared__ __align__(16) ushort_t lA[128 * 32];
    __shared__ __align__(16) ushort_t lB[128 * 32];
    int tid = threadIdx.x;
    int wave = tid >> 6, lane = tid & 63;
    int l15 = lane & 15, q = lane >> 4;
    int mh = wave >> 1, nh = wave & 1;
    int m0 = blockIdx.y * 128, colb = blockIdx.x * 128;

    f32x4 acc[4][4];
#pragma unroll
    for (int i = 0; i < 4; i++)
#pragma unroll
        for (int j = 0; j < 4; j++)
#pragma unroll
            for (int r = 0; r < 4; r++) acc[i][j][r] = 0.f;

    const ushort_t* gA0 = W  + (size_t)(m0 +      (tid >> 2)) * CIN + (tid & 3) * 8;
    const ushort_t* gA1 = W  + (size_t)(m0 + 64 + (tid >> 2)) * CIN + (tid & 3) * 8;
    const ushort_t* gB0 = Xc + (size_t)(colb +      (tid >> 2)) * CIN + (tid & 3) * 8;
    const ushort_t* gB1 = Xc + (size_t)(colb + 64 + (tid >> 2)) * CIN + (tid & 3) * 8;
    ushort_t* la0 = &lA[tid * 8];
    ushort_t* la1 = &lA[2048 + tid * 8];
    ushort_t* lb0 = &lB[tid * 8];
    ushort_t* lb1 = &lB[2048 + tid * 8];

    for (int k0 = 0; k0 < CIN; k0 += 32) {
        gl_lds16(gA0 + k0, la0);
        gl_lds16(gA1 + k0, la1);
        gl_lds16(gB0 + k0, lb0);
        gl_lds16(gB1 + k0, lb1);
        __syncthreads();
        short8 af[4], bf[4];
#pragma unroll
        for (int i = 0; i < 4; i++) {
            af[i] = *(const short8*)&lA[(mh * 64 + i * 16 + l15) * 32 + q * 8];
            bf[i] = *(const short8*)&lB[(nh * 64 + i * 16 + l15) * 32 + q * 8];
        }
#pragma unroll
        for (int mi = 0; mi < 4; mi++)
#pragma unroll
            for (int ni = 0; ni < 4; ni++)
                acc[mi][ni] = __builtin_amdgcn_mfma_f32_16x16x32_bf16(af[mi], bf[ni],
                                                                      acc[mi][ni], 0, 0, 0);
        __syncthreads();
    }

    int col_l = colb + nh * 64 + l15;
#pragma unroll
    for (int mi = 0; mi < 4; mi++) {
#pragma unroll
        for (int r = 0; r < 4; r++) {
            int m = m0 + mh * 64 + mi * 16 + q * 4 + r;
            float sc = gamma[m] * rsqrtf(var[m] + 1e-5f);
            float sh = beta[m] - mean[m] * sc;
#pragma unroll
            for (int ni = 0; ni < 4; ni++) {
                float val = acc[mi][ni][r] * sc + sh;
                int col = col_l + ni * 16;
                if (mode == 0) {
                    out_b[(size_t)m * NCOLS + col] = f2b(val);
                } else {
                    int bb = col >> 12, n = col & 4095;
                    out_f[(size_t)bb * (CIN * NTOK) + (size_t)m * NTOK + n] = val;
                }
            }
        }
    }
}

// ---------------------------------------------------------------------------
// Fused denominator pass (direct stores, no atomics, no cross-lane ops in the
// k-part):
//  blocks 0..1023  : S_q[c][b] = sum_n exp(q[c][b*4096+n])   (one wave/row)
//  blocks 1024..1279: rsums[bh][n] = 1 / sum_d exp(k[d][n])  (thread = 8 tok)
__global__ __launch_bounds__(256) void sum_ker(const ushort_t* __restrict__ qkv,
                                               float* __restrict__ qsums,
                                               float* __restrict__ rsums) {
    int tid = threadIdx.x;
    if (blockIdx.x < 1024) {                     // ---- q row sums (as R1) ----
        int wave = tid >> 6, lane = tid & 63;
        int rid = blockIdx.x * 4 + wave;         // 0..4095
        int c = rid >> 4, b = rid & 15;
        const ushort_t* row = qkv + (size_t)c * NCOLS + b * NTOK;
        float s = 0.f;
#pragma unroll
        for (int j = 0; j < 8; j++) {
            short8 pk = *(const short8*)(row + j * 512 + lane * 8);
#pragma unroll
            for (int i = 0; i < 8; i++) s += __expf(b2f((ushort_t)pk[i]));
        }
        for (int off = 1; off < 64; off <<= 1) s += __shfl_xor(s, off);
        if (lane == 0) qsums[c * 16 + b] = s;
    } else {                                     // ---- k col sums, per head ----
        int kb = blockIdx.x - 1024;              // 0..255
        int bh = kb >> 1, half = kb & 1;
        int b = bh >> 3, h = bh & 7;
        const ushort_t* base = qkv + (size_t)(256 + h * 32) * NCOLS
                                   + b * NTOK + half * 2048 + tid * 8;
        float s[8];
#pragma unroll
        for (int j = 0; j < 8; j++) s[j] = 0.f;
        for (int ch = 0; ch < 32; ch++) {
            short8 kk = *(const short8*)(base + (size_t)ch * NCOLS);
#pragma unroll
            for (int j = 0; j < 8; j++) s[j] += __expf(b2f((ushort_t)kk[j]));
        }
        float* rp = rsums + (size_t)bh * NTOK + half * 2048 + tid * 8;
        f32x4 r0, r1;
#pragma unroll
        for (int j = 0; j < 4; j++) { r0[j] = 1.f / s[j]; r1[j] = 1.f / s[j + 4]; }
        *(f32x4*)rp = r0;
        *(f32x4*)(rp + 4) = r1;
    }
}

// ---------------------------------------------------------------------------
// ctxpart[sl][bh][d][e] = sum_n (exp(k[d][n])*rs[n]) * v[e][n]  over this
// sl's tokens. k-softmax via precomputed reciprocal — NO shuffles, NO fdiv,
// NO atomics (per-sl partial written directly; out_ker sums the 8 partials).
__global__ __launch_bounds__(256) void ctx_ker(const ushort_t* __restrict__ qkv,
                                               const float* __restrict__ rsums,
                                               float* __restrict__ ctxpart) {
    int sl = blockIdx.x, bh = blockIdx.y;
    int b = bh >> 3, h = bh & 7;
    int tid = threadIdx.x, wave = tid >> 6, lane = tid & 63;
    int l31 = lane & 31, l5 = lane >> 5;
    int col0 = b * NTOK + sl * 512 + wave * 128;
    const ushort_t* krow = qkv + (size_t)(256 + h * 32 + l31) * NCOLS + col0 + l5 * 8;
    const ushort_t* vrow = qkv + (size_t)(512 + h * 32 + l31) * NCOLS + col0 + l5 * 8;
    const float* rsp = rsums + (size_t)bh * NTOK + sl * 512 + wave * 128 + l5 * 8;
    f32x16 acc;
#pragma unroll
    for (int i = 0; i < 16; i++) acc[i] = 0.f;
#pragma unroll
    for (int st = 0; st < 8; st++) {
        short8 kf = *(const short8*)(krow + st * 16);
        short8 vf = *(const short8*)(vrow + st * 16);   // v raw (B operand)
        f32x4 ra = *(const f32x4*)(rsp + st * 16);
        f32x4 rb = *(const f32x4*)(rsp + st * 16 + 4);
        short8 af;
#pragma unroll
        for (int j = 0; j < 4; j++)
            af[j] = (short)f2b(__expf(b2f((ushort_t)kf[j])) * ra[j]);
#pragma unroll
        for (int j = 0; j < 4; j++)
            af[j + 4] = (short)f2b(__expf(b2f((ushort_t)kf[j + 4])) * rb[j]);
        acc = __builtin_amdgcn_mfma_f32_32x32x16_bf16(af, vf, acc, 0, 0, 0);
    }
    __shared__ float red[4][1024];
#pragma unroll
    for (int r = 0; r < 16; r++) {
        int d = (r & 3) + 8 * (r >> 2) + 4 * l5;        // C/D row (m74/m101)
        red[wave][d * 32 + l31] = acc[r];
    }
    __syncthreads();
    int i0 = tid * 4;
    f32x4 vv;
#pragma unroll
    for (int i = 0; i < 4; i++)
        vv[i] = red[0][i0 + i] + red[1][i0 + i] + red[2][i0 + i] + red[3][i0 + i];
    *(f32x4*)(ctxpart + ((size_t)sl * 128 + bh) * 1024 + i0) = vv;
}

// ---------------------------------------------------------------------------
// out[e][n] = sum_d ctx[d][e] * (exp(q[d][n])/S_q[d])  -> attT[token][256]
// ctx assembled by summing the 8 per-sl partials during the ctxT fill.
__global__ __launch_bounds__(256) void out_ker(const ushort_t* __restrict__ qkv,
                                               const float* __restrict__ ctxpart,
                                               const float* __restrict__ qsums,
                                               ushort_t* __restrict__ attT) {
    int sl = blockIdx.x, bh = blockIdx.y;
    int b = bh >> 3, h = bh & 7;
    int tid = threadIdx.x, wave = tid >> 6, lane = tid & 63;
    int l31 = lane & 31, l5 = lane >> 5;
    __shared__ __align__(16) ushort_t ctxT[32 * 40];
    __shared__ __align__(16) ushort_t qT[256 * 40];
    __shared__ __align__(16) ushort_t obuf[4][32 * 40];

    {
        int i0 = tid * 4;
        f32x4 v;
#pragma unroll
        for (int i = 0; i < 4; i++) v[i] = 0.f;
#pragma unroll
        for (int s = 0; s < 8; s++)
            v += *(const f32x4*)(ctxpart + ((size_t)s * 128 + bh) * 1024 + i0);
#pragma unroll
        for (int i = 0; i < 4; i++) {
            int idx = i0 + i;
            int d = idx >> 5, e = idx & 31;
            ctxT[e * 40 + d] = f2b(v[i]);        // k-norm already in ctx
        }
    }
    __syncthreads();
    short8 a0 = *(const short8*)(ctxT + l31 * 40 + l5 * 8);
    short8 a1 = *(const short8*)(ctxT + l31 * 40 + 16 + l5 * 8);

    const ushort_t* qbase = qkv + (size_t)(h * 32) * NCOLS;
    int segbase = b * NTOK + sl * 512;
    int d = tid & 31, t8 = (tid >> 5) * 8;
    float sq = 1.f / qsums[(h * 32 + d) * 16 + b];     // per-thread row scale

    for (int nc = 0; nc < 2; nc++) {
        int gcol0 = segbase + nc * 256;
#pragma unroll
        for (int jj = 0; jj < 4; jj++) {
            int tok8 = jj * 64 + t8;
            short8 pk = *(const short8*)(qbase + (size_t)d * NCOLS + gcol0 + tok8);
#pragma unroll
            for (int j = 0; j < 8; j++)
                qT[(tok8 + j) * 40 + d] = f2b(__expf(b2f((ushort_t)pk[j])) * sq);
        }
        __syncthreads();
#pragma unroll
        for (int ti = 0; ti < 2; ti++) {
            int tok0 = (wave + ti * 4) * 32;
            f32x16 acc;
#pragma unroll
            for (int i = 0; i < 16; i++) acc[i] = 0.f;
            short8 b0 = *(const short8*)(qT + (size_t)(tok0 + l31) * 40 + l5 * 8);
            short8 b1 = *(const short8*)(qT + (size_t)(tok0 + l31) * 40 + 16 + l5 * 8);
            acc = __builtin_amdgcn_mfma_f32_32x32x16_bf16(a0, b0, acc, 0, 0, 0);
            acc = __builtin_amdgcn_mfma_f32_32x32x16_bf16(a1, b1, acc, 0, 0, 0);
#pragma unroll
            for (int r = 0; r < 16; r++) {
                int e = (r & 3) + 8 * (r >> 2) + 4 * l5;
                obuf[wave][l31 * 40 + e] = f2b(acc[r]);
            }
            __syncthreads();
            {
                int tok = lane >> 1, half = lane & 1;
                const ushort_t* srcp = &obuf[wave][tok * 40 + half * 16];
                short8 r0 = *(const short8*)srcp;
                short8 r1 = *(const short8*)(srcp + 8);
                size_t g = (size_t)(gcol0 + tok0 + tok) * 256 + h * 32 + half * 16;
                *(short8*)(attT + g) = r0;
                *(short8*)(attT + g + 8) = r1;
            }
            __syncthreads();
        }
        __syncthreads();
    }
}

// ---------------------------------------------------------------------------
extern "C" void kernel_launch(void* const* d_in, const int* in_sizes, int n_in,
                              void* d_out, int out_size, void* d_ws, size_t ws_size,
                              hipStream_t stream) {
    const float* x          = (const float*)d_in[0];
    const float* qkv_w      = (const float*)d_in[1];
    const float* qkv_gamma  = (const float*)d_in[2];
    const float* qkv_beta   = (const float*)d_in[3];
    const float* qkv_mean   = (const float*)d_in[4];
    const float* qkv_var    = (const float*)d_in[5];
    const float* proj_w     = (const float*)d_in[6];
    const float* proj_gamma = (const float*)d_in[7];
    const float* proj_beta  = (const float*)d_in[8];
    const float* proj_mean  = (const float*)d_in[9];
    const float* proj_var   = (const float*)d_in[10];

    ushort_t* wqb = (ushort_t*)d_ws;                 // 393,216 B
    ushort_t* wpb = wqb + 768 * 256;                 // 131,072 B
    ushort_t* xt  = wpb + 256 * 256;                 // 33.5 MB (also attT later)
    ushort_t* qkv = xt + (size_t)NCOLS * CIN;        // 100.7 MB
    float* out     = (float*)d_out;
    float* ctxpart = (float*)d_out;                  // 4 MB scratch in d_out
    float* rsums   = ctxpart + 8 * 128 * 1024;       // 2 MB
    float* qsums   = rsums + 128 * NTOK;             // 16 KB

    prep_x<<<1024, 256, 0, stream>>>(x, xt, qkv_w, proj_w, wqb, wpb);
    gemm128<<<dim3(512, 6), 256, 0, stream>>>(wqb, xt, qkv_gamma, qkv_beta,
                                              qkv_mean, qkv_var, qkv, nullptr, 0);
    sum_ker<<<1280, 256, 0, stream>>>(qkv, qsums, rsums);
    ctx_ker<<<dim3(8, 128), 256, 0, stream>>>(qkv, rsums, ctxpart);
    out_ker<<<dim3(8, 128), 256, 0, stream>>>(qkv, ctxpart, qsums, xt);
    gemm128<<<dim3(512, 2), 256, 0, stream>>>(wpb, xt, proj_gamma, proj_beta,
                                              proj_mean, proj_var, nullptr, out, 1);
}

// Round 8
// 281.216 us; speedup vs baseline: 1.3675x; 1.0392x over previous
//
#include <hip/hip_runtime.h>

typedef unsigned short ushort_t;
typedef unsigned int u32;
typedef short short8 __attribute__((ext_vector_type(8)));
typedef float f32x4 __attribute__((ext_vector_type(4)));
typedef float f32x16 __attribute__((ext_vector_type(16)));

#define NTOK 4096
#define NCOLS 65536
#define CIN 256

__device__ __forceinline__ float b2f(ushort_t u) {
    union { unsigned int i; float f; } v; v.i = ((unsigned int)u) << 16; return v.f;
}
__device__ __forceinline__ ushort_t f2b(float f) {
    union { float f; unsigned int i; } v; v.f = f;
    unsigned int r = v.i + 0x7FFFu + ((v.i >> 16) & 1u);   // RNE
    return (ushort_t)(r >> 16);
}

__device__ __forceinline__ void gl_lds16(const ushort_t* g, ushort_t* l) {
    __builtin_amdgcn_global_load_lds(
        (const __attribute__((address_space(1))) u32*)(const void*)g,
        (__attribute__((address_space(3))) u32*)(void*)l,
        16, 0, 0);
}

// ---------------------------------------------------------------------------
// prep: x fp32 [16][256][4096] -> xt bf16 [65536][256]  (LDS-tiled transpose)
//       + weights fp32->bf16 (folded cvt_w)
__global__ __launch_bounds__(256) void prep_x(const float* __restrict__ x,
                                              ushort_t* __restrict__ xt,
                                              const float* __restrict__ wq,
                                              const float* __restrict__ wp,
                                              ushort_t* __restrict__ wqb,
                                              ushort_t* __restrict__ wpb) {
    __shared__ ushort_t lds[64 * 264];           // 33,792 B; 528B rows (16B-aligned)
    int tid = threadIdx.x;

    // folded cvt_w: 1 weight elem per thread
    int i = blockIdx.x * 256 + tid;              // 0 .. 262143
    if (i < 768 * 256) wqb[i] = f2b(wq[i]);
    else               wpb[i - 768 * 256] = f2b(wp[i - 768 * 256]);

    int g0 = blockIdx.x * 64;                    // 64 tokens per block
    int b = g0 >> 12, n0 = g0 & 4095;
    const float* src = x + (size_t)b * (CIN * NTOK);
    int tn = tid & 63, cg = tid >> 6;
    for (int c4 = 0; c4 < 64; c4++) {
        int c = c4 * 4 + cg;
        lds[tn * 264 + c] = f2b(src[(size_t)c * NTOK + n0 + tn]);
    }
    __syncthreads();
    int tok = tid >> 2, c8 = (tid & 3) * 8;
    ushort_t* dst = xt + (size_t)(g0 + tok) * CIN + c8;
#pragma unroll
    for (int j = 0; j < 8; j++)
        *(short8*)(dst + j * 32) = *(const short8*)&lds[tok * 264 + c8 + j * 32];
}

// ---------------------------------------------------------------------------
// R1-proven 128x128-tile GEMM + thin BN epilogue. 1-D grid with T1 XCD-aware
// swizzle: XCD j (= bid%8) owns col-panels [j*K, (j+1)*K), m-fastest within,
// so each XCD's 4 MB xt slice stays L2-resident across all m-tiles.
// mode 0: out_b[m*65536 + col] bf16   |   mode 1: out_f[b][m][n] fp32
__global__ __launch_bounds__(256) void gemm128(const ushort_t* __restrict__ W,
                                               const ushort_t* __restrict__ Xc,
                                               const float* __restrict__ gamma,
                                               const float* __restrict__ beta,
                                               const float* __restrict__ mean,
                                               const float* __restrict__ var,
                                               ushort_t* __restrict__ out_b,
                                               float* __restrict__ out_f,
                                               int mtiles, int mode) {
    __shared__ __align__(16) ushort_t lA[128 * 32];
    __shared__ __align__(16) ushort_t lB[128 * 32];
    int tid = threadIdx.x;
    int wave = tid >> 6, lane = tid & 63;
    int l15 = lane & 15, q = lane >> 4;
    int mh = wave >> 1, nh = wave & 1;

    // XCD swizzle: cpx = nwg/8 = mtiles*64; bijective since nwg%8==0
    int bid = blockIdx.x;
    int swz = (bid & 7) * (mtiles * 64) + (bid >> 3);
    int m0 = (swz % mtiles) * 128, colb = (swz / mtiles) * 128;

    f32x4 acc[4][4];
#pragma unroll
    for (int i = 0; i < 4; i++)
#pragma unroll
        for (int j = 0; j < 4; j++)
#pragma unroll
            for (int r = 0; r < 4; r++) acc[i][j][r] = 0.f;

    const ushort_t* gA0 = W  + (size_t)(m0 +      (tid >> 2)) * CIN + (tid & 3) * 8;
    const ushort_t* gA1 = W  + (size_t)(m0 + 64 + (tid >> 2)) * CIN + (tid & 3) * 8;
    const ushort_t* gB0 = Xc + (size_t)(colb +      (tid >> 2)) * CIN + (tid & 3) * 8;
    const ushort_t* gB1 = Xc + (size_t)(colb + 64 + (tid >> 2)) * CIN + (tid & 3) * 8;
    ushort_t* la0 = &lA[tid * 8];
    ushort_t* la1 = &lA[2048 + tid * 8];
    ushort_t* lb0 = &lB[tid * 8];
    ushort_t* lb1 = &lB[2048 + tid * 8];

    for (int k0 = 0; k0 < CIN; k0 += 32) {
        gl_lds16(gA0 + k0, la0);
        gl_lds16(gA1 + k0, la1);
        gl_lds16(gB0 + k0, lb0);
        gl_lds16(gB1 + k0, lb1);
        __syncthreads();
        short8 af[4], bf[4];
#pragma unroll
        for (int i = 0; i < 4; i++) {
            af[i] = *(const short8*)&lA[(mh * 64 + i * 16 + l15) * 32 + q * 8];
            bf[i] = *(const short8*)&lB[(nh * 64 + i * 16 + l15) * 32 + q * 8];
        }
#pragma unroll
        for (int mi = 0; mi < 4; mi++)
#pragma unroll
            for (int ni = 0; ni < 4; ni++)
                acc[mi][ni] = __builtin_amdgcn_mfma_f32_16x16x32_bf16(af[mi], bf[ni],
                                                                      acc[mi][ni], 0, 0, 0);
        __syncthreads();
    }

    int col_l = colb + nh * 64 + l15;
#pragma unroll
    for (int mi = 0; mi < 4; mi++) {
#pragma unroll
        for (int r = 0; r < 4; r++) {
            int m = m0 + mh * 64 + mi * 16 + q * 4 + r;
            float sc = gamma[m] * rsqrtf(var[m] + 1e-5f);
            float sh = beta[m] - mean[m] * sc;
#pragma unroll
            for (int ni = 0; ni < 4; ni++) {
                float val = acc[mi][ni][r] * sc + sh;
                int col = col_l + ni * 16;
                if (mode == 0) {
                    out_b[(size_t)m * NCOLS + col] = f2b(val);
                } else {
                    int bb = col >> 12, n = col & 4095;
                    out_f[(size_t)bb * (CIN * NTOK) + (size_t)m * NTOK + n] = val;
                }
            }
        }
    }
}

// ---------------------------------------------------------------------------
// Fused denominator pass (direct stores, no atomics, no cross-lane ops in the
// k-part):
//  blocks 0..1023  : S_q[c][b] = sum_n exp(q[c][b*4096+n])   (one wave/row)
//  blocks 1024..1279: rsums[bh][n] = 1 / sum_d exp(k[d][n])  (thread = 8 tok)
__global__ __launch_bounds__(256) void sum_ker(const ushort_t* __restrict__ qkv,
                                               float* __restrict__ qsums,
                                               float* __restrict__ rsums) {
    int tid = threadIdx.x;
    if (blockIdx.x < 1024) {                     // ---- q row sums (as R1) ----
        int wave = tid >> 6, lane = tid & 63;
        int rid = blockIdx.x * 4 + wave;         // 0..4095
        int c = rid >> 4, b = rid & 15;
        const ushort_t* row = qkv + (size_t)c * NCOLS + b * NTOK;
        float s = 0.f;
#pragma unroll
        for (int j = 0; j < 8; j++) {
            short8 pk = *(const short8*)(row + j * 512 + lane * 8);
#pragma unroll
            for (int i = 0; i < 8; i++) s += __expf(b2f((ushort_t)pk[i]));
        }
        for (int off = 1; off < 64; off <<= 1) s += __shfl_xor(s, off);
        if (lane == 0) qsums[c * 16 + b] = s;
    } else {                                     // ---- k col sums, per head ----
        int kb = blockIdx.x - 1024;              // 0..255
        int bh = kb >> 1, half = kb & 1;
        int b = bh >> 3, h = bh & 7;
        const ushort_t* base = qkv + (size_t)(256 + h * 32) * NCOLS
                                   + b * NTOK + half * 2048 + tid * 8;
        float s[8];
#pragma unroll
        for (int j = 0; j < 8; j++) s[j] = 0.f;
        for (int ch = 0; ch < 32; ch++) {
            short8 kk = *(const short8*)(base + (size_t)ch * NCOLS);
#pragma unroll
            for (int j = 0; j < 8; j++) s[j] += __expf(b2f((ushort_t)kk[j]));
        }
        float* rp = rsums + (size_t)bh * NTOK + half * 2048 + tid * 8;
        f32x4 r0, r1;
#pragma unroll
        for (int j = 0; j < 4; j++) { r0[j] = 1.f / s[j]; r1[j] = 1.f / s[j + 4]; }
        *(f32x4*)rp = r0;
        *(f32x4*)(rp + 4) = r1;
    }
}

// ---------------------------------------------------------------------------
// ctxpart[sl][bh][d][e] = sum_n (exp(k[d][n])*rs[n]) * v[e][n]  over this
// sl's tokens. k-softmax via precomputed reciprocal — NO shuffles, NO fdiv,
// NO atomics (per-sl partial written directly; out_ker sums the 8 partials).
__global__ __launch_bounds__(256) void ctx_ker(const ushort_t* __restrict__ qkv,
                                               const float* __restrict__ rsums,
                                               float* __restrict__ ctxpart) {
    int sl = blockIdx.x, bh = blockIdx.y;
    int b = bh >> 3, h = bh & 7;
    int tid = threadIdx.x, wave = tid >> 6, lane = tid & 63;
    int l31 = lane & 31, l5 = lane >> 5;
    int col0 = b * NTOK + sl * 512 + wave * 128;
    const ushort_t* krow = qkv + (size_t)(256 + h * 32 + l31) * NCOLS + col0 + l5 * 8;
    const ushort_t* vrow = qkv + (size_t)(512 + h * 32 + l31) * NCOLS + col0 + l5 * 8;
    const float* rsp = rsums + (size_t)bh * NTOK + sl * 512 + wave * 128 + l5 * 8;
    f32x16 acc;
#pragma unroll
    for (int i = 0; i < 16; i++) acc[i] = 0.f;
#pragma unroll
    for (int st = 0; st < 8; st++) {
        short8 kf = *(const short8*)(krow + st * 16);
        short8 vf = *(const short8*)(vrow + st * 16);   // v raw (B operand)
        f32x4 ra = *(const f32x4*)(rsp + st * 16);
        f32x4 rb = *(const f32x4*)(rsp + st * 16 + 4);
        short8 af;
#pragma unroll
        for (int j = 0; j < 4; j++)
            af[j] = (short)f2b(__expf(b2f((ushort_t)kf[j])) * ra[j]);
#pragma unroll
        for (int j = 0; j < 4; j++)
            af[j + 4] = (short)f2b(__expf(b2f((ushort_t)kf[j + 4])) * rb[j]);
        acc = __builtin_amdgcn_mfma_f32_32x32x16_bf16(af, vf, acc, 0, 0, 0);
    }
    __shared__ float red[4][1024];
#pragma unroll
    for (int r = 0; r < 16; r++) {
        int d = (r & 3) + 8 * (r >> 2) + 4 * l5;        // C/D row (m74/m101)
        red[wave][d * 32 + l31] = acc[r];
    }
    __syncthreads();
    int i0 = tid * 4;
    f32x4 vv;
#pragma unroll
    for (int i = 0; i < 4; i++)
        vv[i] = red[0][i0 + i] + red[1][i0 + i] + red[2][i0 + i] + red[3][i0 + i];
    *(f32x4*)(ctxpart + ((size_t)sl * 128 + bh) * 1024 + i0) = vv;
}

// ---------------------------------------------------------------------------
// out[e][n] = sum_d ctx[d][e] * (exp(q[d][n])/S_q[d])  -> attT[token][256]
// ctx assembled by summing the 8 per-sl partials during the ctxT fill.
// obuf is per-wave -> no barriers needed around its write/read (in-order DS
// pipe within a wave); only the nc-end barrier protects qT reuse.
__global__ __launch_bounds__(256) void out_ker(const ushort_t* __restrict__ qkv,
                                               const float* __restrict__ ctxpart,
                                               const float* __restrict__ qsums,
                                               ushort_t* __restrict__ attT) {
    int sl = blockIdx.x, bh = blockIdx.y;
    int b = bh >> 3, h = bh & 7;
    int tid = threadIdx.x, wave = tid >> 6, lane = tid & 63;
    int l31 = lane & 31, l5 = lane >> 5;
    __shared__ __align__(16) ushort_t ctxT[32 * 40];
    __shared__ __align__(16) ushort_t qT[256 * 40];
    __shared__ __align__(16) ushort_t obuf[4][32 * 40];

    {
        int i0 = tid * 4;
        f32x4 v;
#pragma unroll
        for (int i = 0; i < 4; i++) v[i] = 0.f;
#pragma unroll
        for (int s = 0; s < 8; s++)
            v += *(const f32x4*)(ctxpart + ((size_t)s * 128 + bh) * 1024 + i0);
#pragma unroll
        for (int i = 0; i < 4; i++) {
            int idx = i0 + i;
            int d = idx >> 5, e = idx & 31;
            ctxT[e * 40 + d] = f2b(v[i]);        // k-norm already in ctx
        }
    }
    __syncthreads();
    short8 a0 = *(const short8*)(ctxT + l31 * 40 + l5 * 8);
    short8 a1 = *(const short8*)(ctxT + l31 * 40 + 16 + l5 * 8);

    const ushort_t* qbase = qkv + (size_t)(h * 32) * NCOLS;
    int segbase = b * NTOK + sl * 512;
    int d = tid & 31, t8 = (tid >> 5) * 8;
    float sq = 1.f / qsums[(h * 32 + d) * 16 + b];     // per-thread row scale

    for (int nc = 0; nc < 2; nc++) {
        int gcol0 = segbase + nc * 256;
#pragma unroll
        for (int jj = 0; jj < 4; jj++) {
            int tok8 = jj * 64 + t8;
            short8 pk = *(const short8*)(qbase + (size_t)d * NCOLS + gcol0 + tok8);
#pragma unroll
            for (int j = 0; j < 8; j++)
                qT[(tok8 + j) * 40 + d] = f2b(__expf(b2f((ushort_t)pk[j])) * sq);
        }
        __syncthreads();
#pragma unroll
        for (int ti = 0; ti < 2; ti++) {
            int tok0 = (wave + ti * 4) * 32;
            f32x16 acc;
#pragma unroll
            for (int i = 0; i < 16; i++) acc[i] = 0.f;
            short8 b0 = *(const short8*)(qT + (size_t)(tok0 + l31) * 40 + l5 * 8);
            short8 b1 = *(const short8*)(qT + (size_t)(tok0 + l31) * 40 + 16 + l5 * 8);
            acc = __builtin_amdgcn_mfma_f32_32x32x16_bf16(a0, b0, acc, 0, 0, 0);
            acc = __builtin_amdgcn_mfma_f32_32x32x16_bf16(a1, b1, acc, 0, 0, 0);
#pragma unroll
            for (int r = 0; r < 16; r++) {
                int e = (r & 3) + 8 * (r >> 2) + 4 * l5;
                obuf[wave][l31 * 40 + e] = f2b(acc[r]);
            }
            {
                int tok = lane >> 1, half = lane & 1;
                const ushort_t* srcp = &obuf[wave][tok * 40 + half * 16];
                short8 r0 = *(const short8*)srcp;
                short8 r1 = *(const short8*)(srcp + 8);
                size_t g = (size_t)(gcol0 + tok0 + tok) * 256 + h * 32 + half * 16;
                *(short8*)(attT + g) = r0;
                *(short8*)(attT + g + 8) = r1;
            }
        }
        __syncthreads();
    }
}

// ---------------------------------------------------------------------------
extern "C" void kernel_launch(void* const* d_in, const int* in_sizes, int n_in,
                              void* d_out, int out_size, void* d_ws, size_t ws_size,
                              hipStream_t stream) {
    const float* x          = (const float*)d_in[0];
    const float* qkv_w      = (const float*)d_in[1];
    const float* qkv_gamma  = (const float*)d_in[2];
    const float* qkv_beta   = (const float*)d_in[3];
    const float* qkv_mean   = (const float*)d_in[4];
    const float* qkv_var    = (const float*)d_in[5];
    const float* proj_w     = (const float*)d_in[6];
    const float* proj_gamma = (const float*)d_in[7];
    const float* proj_beta  = (const float*)d_in[8];
    const float* proj_mean  = (const float*)d_in[9];
    const float* proj_var   = (const float*)d_in[10];

    ushort_t* wqb = (ushort_t*)d_ws;                 // 393,216 B
    ushort_t* wpb = wqb + 768 * 256;                 // 131,072 B
    ushort_t* xt  = wpb + 256 * 256;                 // 33.5 MB (also attT later)
    ushort_t* qkv = xt + (size_t)NCOLS * CIN;        // 100.7 MB
    float* out     = (float*)d_out;
    float* ctxpart = (float*)d_out;                  // 4 MB scratch in d_out
    float* rsums   = ctxpart + 8 * 128 * 1024;       // 2 MB
    float* qsums   = rsums + 128 * NTOK;             // 16 KB

    prep_x<<<1024, 256, 0, stream>>>(x, xt, qkv_w, proj_w, wqb, wpb);
    gemm128<<<3072, 256, 0, stream>>>(wqb, xt, qkv_gamma, qkv_beta,
                                      qkv_mean, qkv_var, qkv, nullptr, 6, 0);
    sum_ker<<<1280, 256, 0, stream>>>(qkv, qsums, rsums);
    ctx_ker<<<dim3(8, 128), 256, 0, stream>>>(qkv, rsums, ctxpart);
    out_ker<<<dim3(8, 128), 256, 0, stream>>>(qkv, ctxpart, qsums, xt);
    gemm128<<<1024, 256, 0, stream>>>(wpb, xt, proj_gamma, proj_beta,
                                      proj_mean, proj_var, nullptr, out, 2, 1);
}

// Round 9
// 263.474 us; speedup vs baseline: 1.4596x; 1.0673x over previous
//
#include <hip/hip_runtime.h>

typedef unsigned short ushort_t;
typedef unsigned int u32;
typedef short short8 __attribute__((ext_vector_type(8)));
typedef float f32x4 __attribute__((ext_vector_type(4)));
typedef float f32x16 __attribute__((ext_vector_type(16)));

#define NTOK 4096
#define NCOLS 65536
#define CIN 256

__device__ __forceinline__ float b2f(ushort_t u) {
    union { unsigned int i; float f; } v; v.i = ((unsigned int)u) << 16; return v.f;
}
__device__ __forceinline__ ushort_t f2b(float f) {
    union { float f; unsigned int i; } v; v.f = f;
    unsigned int r = v.i + 0x7FFFu + ((v.i >> 16) & 1u);   // RNE
    return (ushort_t)(r >> 16);
}

__device__ __forceinline__ void gl_lds16(const ushort_t* g, ushort_t* l) {
    __builtin_amdgcn_global_load_lds(
        (const __attribute__((address_space(1))) u32*)(const void*)g,
        (__attribute__((address_space(3))) u32*)(void*)l,
        16, 0, 0);
}

// ---------------------------------------------------------------------------
// prep: x fp32 [16][256][4096] -> xt bf16 [65536][256]  (LDS-tiled transpose)
//       + weights fp32->bf16 (folded cvt_w)
__global__ __launch_bounds__(256) void prep_x(const float* __restrict__ x,
                                              ushort_t* __restrict__ xt,
                                              const float* __restrict__ wq,
                                              const float* __restrict__ wp,
                                              ushort_t* __restrict__ wqb,
                                              ushort_t* __restrict__ wpb) {
    __shared__ ushort_t lds[64 * 264];           // 33,792 B; 528B rows (16B-aligned)
    int tid = threadIdx.x;

    // folded cvt_w: 1 weight elem per thread
    int i = blockIdx.x * 256 + tid;              // 0 .. 262143
    if (i < 768 * 256) wqb[i] = f2b(wq[i]);
    else               wpb[i - 768 * 256] = f2b(wp[i - 768 * 256]);

    int g0 = blockIdx.x * 64;                    // 64 tokens per block
    int b = g0 >> 12, n0 = g0 & 4095;
    const float* src = x + (size_t)b * (CIN * NTOK);
    int tn = tid & 63, cg = tid >> 6;
    for (int c4 = 0; c4 < 64; c4++) {
        int c = c4 * 4 + cg;
        lds[tn * 264 + c] = f2b(src[(size_t)c * NTOK + n0 + tn]);
    }
    __syncthreads();
    int tok = tid >> 2, c8 = (tid & 3) * 8;
    ushort_t* dst = xt + (size_t)(g0 + tok) * CIN + c8;
#pragma unroll
    for (int j = 0; j < 8; j++)
        *(short8*)(dst + j * 32) = *(const short8*)&lds[tok * 264 + c8 + j * 32];
}

// ---------------------------------------------------------------------------
// R1-proven 128x128-tile GEMM + thin BN epilogue + T1 XCD swizzle (R8, -7.6µs)
// + LDS k-group XOR swizzle (rule 21: swizzle SOURCE global addr, linear LDS
// dest via gl_lds, same XOR on read): 8-way ds_read_b128 conflict -> 4-way.
// mode 0: out_b[m*65536 + col] bf16   |   mode 1: out_f[b][m][n] fp32
__global__ __launch_bounds__(256) void gemm128(const ushort_t* __restrict__ W,
                                               const ushort_t* __restrict__ Xc,
                                               const float* __restrict__ gamma,
                                               const float* __restrict__ beta,
                                               const float* __restrict__ mean,
                                               const float* __restrict__ var,
                                               ushort_t* __restrict__ out_b,
                                               float* __restrict__ out_f,
                                               int mtiles, int mode) {
    __shared__ __align__(16) ushort_t lA[128 * 32];
    __shared__ __align__(16) ushort_t lB[128 * 32];
    int tid = threadIdx.x;
    int wave = tid >> 6, lane = tid & 63;
    int l15 = lane & 15, q = lane >> 4;
    int mh = wave >> 1, nh = wave & 1;

    // XCD swizzle: cpx = nwg/8 = mtiles*64; bijective since nwg%8==0
    int bid = blockIdx.x;
    int swz = (bid & 7) * (mtiles * 64) + (bid >> 3);
    int m0 = (swz % mtiles) * 128, colb = (swz / mtiles) * 128;

    f32x4 acc[4][4];
#pragma unroll
    for (int i = 0; i < 4; i++)
#pragma unroll
        for (int j = 0; j < 4; j++)
#pragma unroll
            for (int r = 0; r < 4; r++) acc[i][j][r] = 0.f;

    // staging: thread covers (row = tid>>2, k-group tid&3); source k-group is
    // XOR-swizzled by row&3 so LDS slot (row, g) holds global chunk g^(row&3)
    int xoff = (((tid & 3) ^ ((tid >> 2) & 3)) * 8);
    const ushort_t* gA0 = W  + (size_t)(m0 +      (tid >> 2)) * CIN + xoff;
    const ushort_t* gA1 = W  + (size_t)(m0 + 64 + (tid >> 2)) * CIN + xoff;
    const ushort_t* gB0 = Xc + (size_t)(colb +      (tid >> 2)) * CIN + xoff;
    const ushort_t* gB1 = Xc + (size_t)(colb + 64 + (tid >> 2)) * CIN + xoff;
    ushort_t* la0 = &lA[tid * 8];
    ushort_t* la1 = &lA[2048 + tid * 8];
    ushort_t* lb0 = &lB[tid * 8];
    ushort_t* lb1 = &lB[2048 + tid * 8];

    int qa = (q ^ (l15 & 3)) * 8;                // read-side XOR (row&3 == l15&3)

    for (int k0 = 0; k0 < CIN; k0 += 32) {
        gl_lds16(gA0 + k0, la0);
        gl_lds16(gA1 + k0, la1);
        gl_lds16(gB0 + k0, lb0);
        gl_lds16(gB1 + k0, lb1);
        __syncthreads();
        short8 af[4], bf[4];
#pragma unroll
        for (int i = 0; i < 4; i++) {
            af[i] = *(const short8*)&lA[(mh * 64 + i * 16 + l15) * 32 + qa];
            bf[i] = *(const short8*)&lB[(nh * 64 + i * 16 + l15) * 32 + qa];
        }
#pragma unroll
        for (int mi = 0; mi < 4; mi++)
#pragma unroll
            for (int ni = 0; ni < 4; ni++)
                acc[mi][ni] = __builtin_amdgcn_mfma_f32_16x16x32_bf16(af[mi], bf[ni],
                                                                      acc[mi][ni], 0, 0, 0);
        __syncthreads();
    }

    int col_l = colb + nh * 64 + l15;
#pragma unroll
    for (int mi = 0; mi < 4; mi++) {
#pragma unroll
        for (int r = 0; r < 4; r++) {
            int m = m0 + mh * 64 + mi * 16 + q * 4 + r;
            float sc = gamma[m] * rsqrtf(var[m] + 1e-5f);
            float sh = beta[m] - mean[m] * sc;
#pragma unroll
            for (int ni = 0; ni < 4; ni++) {
                float val = acc[mi][ni][r] * sc + sh;
                int col = col_l + ni * 16;
                if (mode == 0) {
                    out_b[(size_t)m * NCOLS + col] = f2b(val);
                } else {
                    int bb = col >> 12, n = col & 4095;
                    out_f[(size_t)bb * (CIN * NTOK) + (size_t)m * NTOK + n] = val;
                }
            }
        }
    }
}

// ---------------------------------------------------------------------------
// ctx kernel with fused denominators (sum_ker eliminated):
//  pre-pass A: rsm[tok] = 1/sum_d exp(k[d][tok])  (d-ascending — bitwise ==
//              old sum_ker order; block-local 512 tokens, coalesced u32 loads)
//  pre-pass B: qpart[sl][bh][ch] = sum over this sl's 512 tokens of exp(q)
//              (out_ker sums the 8 partials — no atomics)
//  main: ctxpart[sl][bh][d][e] = sum_n (exp(k[d][n])*rsm[n]) * v[e][n]
__global__ __launch_bounds__(256) void ctx_ker(const ushort_t* __restrict__ qkv,
                                               float* __restrict__ ctxpart,
                                               float* __restrict__ qpart) {
    int sl = blockIdx.x, bh = blockIdx.y;
    int b = bh >> 3, h = bh & 7;
    int tid = threadIdx.x, wave = tid >> 6, lane = tid & 63;
    int l31 = lane & 31, l5 = lane >> 5;
    int colbase = b * NTOK + sl * 512;

    __shared__ float rsm[512];
    __shared__ float red2[256];

    {   // pre-pass A: per-token k-denominator (2 tokens/thread, u32 loads)
        const ushort_t* kb = qkv + (size_t)(256 + h * 32) * NCOLS + colbase + tid * 2;
        float s0 = 0.f, s1 = 0.f;
#pragma unroll
        for (int d = 0; d < 32; d++) {
            u32 w = *(const u32*)(kb + (size_t)d * NCOLS);
            s0 += __expf(b2f((ushort_t)(w & 0xffffu)));
            s1 += __expf(b2f((ushort_t)(w >> 16)));
        }
        rsm[tid * 2]     = 1.f / s0;
        rsm[tid * 2 + 1] = 1.f / s1;
    }
    {   // pre-pass B: q partial sums (thread = (ch, 64-token slot))
        int ch = tid >> 3, slot = tid & 7;
        const ushort_t* qb = qkv + (size_t)(h * 32 + ch) * NCOLS + colbase + slot * 64;
        float s = 0.f;
#pragma unroll
        for (int j = 0; j < 8; j++) {
            short8 pk = *(const short8*)(qb + j * 8);
#pragma unroll
            for (int i = 0; i < 8; i++) s += __expf(b2f((ushort_t)pk[i]));
        }
        red2[tid] = s;
    }
    __syncthreads();
    if (tid < 32) {
        float ss = 0.f;
#pragma unroll
        for (int k = 0; k < 8; k++) ss += red2[tid * 8 + k];
        qpart[((size_t)sl * 128 + bh) * 32 + tid] = ss;
    }

    int col0 = colbase + wave * 128;
    const ushort_t* krow = qkv + (size_t)(256 + h * 32 + l31) * NCOLS + col0 + l5 * 8;
    const ushort_t* vrow = qkv + (size_t)(512 + h * 32 + l31) * NCOLS + col0 + l5 * 8;
    int rbase = wave * 128 + l5 * 8;
    f32x16 acc;
#pragma unroll
    for (int i = 0; i < 16; i++) acc[i] = 0.f;
#pragma unroll
    for (int st = 0; st < 8; st++) {
        short8 kf = *(const short8*)(krow + st * 16);
        short8 vf = *(const short8*)(vrow + st * 16);   // v raw (B operand)
        f32x4 ra = *(const f32x4*)&rsm[rbase + st * 16];
        f32x4 rb = *(const f32x4*)&rsm[rbase + st * 16 + 4];
        short8 af;
#pragma unroll
        for (int j = 0; j < 4; j++)
            af[j] = (short)f2b(__expf(b2f((ushort_t)kf[j])) * ra[j]);
#pragma unroll
        for (int j = 0; j < 4; j++)
            af[j + 4] = (short)f2b(__expf(b2f((ushort_t)kf[j + 4])) * rb[j]);
        acc = __builtin_amdgcn_mfma_f32_32x32x16_bf16(af, vf, acc, 0, 0, 0);
    }
    __shared__ float red[4][1024];
#pragma unroll
    for (int r = 0; r < 16; r++) {
        int d = (r & 3) + 8 * (r >> 2) + 4 * l5;        // C/D row (m74/m101)
        red[wave][d * 32 + l31] = acc[r];
    }
    __syncthreads();
    int i0 = tid * 4;
    f32x4 vv;
#pragma unroll
    for (int i = 0; i < 4; i++)
        vv[i] = red[0][i0 + i] + red[1][i0 + i] + red[2][i0 + i] + red[3][i0 + i];
    *(f32x4*)(ctxpart + ((size_t)sl * 128 + bh) * 1024 + i0) = vv;
}

// ---------------------------------------------------------------------------
// out[e][n] = sum_d ctx[d][e] * (exp(q[d][n])/S_q[d])  -> attT[token][256]
// ctx = sum of 8 ctxpart slices; S_q = sum of 8 qpart slices (no atomics).
__global__ __launch_bounds__(256) void out_ker(const ushort_t* __restrict__ qkv,
                                               const float* __restrict__ ctxpart,
                                               const float* __restrict__ qpart,
                                               ushort_t* __restrict__ attT) {
    int sl = blockIdx.x, bh = blockIdx.y;
    int b = bh >> 3, h = bh & 7;
    int tid = threadIdx.x, wave = tid >> 6, lane = tid & 63;
    int l31 = lane & 31, l5 = lane >> 5;
    __shared__ __align__(16) ushort_t ctxT[32 * 40];
    __shared__ __align__(16) ushort_t qT[256 * 40];
    __shared__ __align__(16) ushort_t obuf[4][32 * 40];

    {
        int i0 = tid * 4;
        f32x4 v;
#pragma unroll
        for (int i = 0; i < 4; i++) v[i] = 0.f;
#pragma unroll
        for (int s = 0; s < 8; s++)
            v += *(const f32x4*)(ctxpart + ((size_t)s * 128 + bh) * 1024 + i0);
#pragma unroll
        for (int i = 0; i < 4; i++) {
            int idx = i0 + i;
            int d = idx >> 5, e = idx & 31;
            ctxT[e * 40 + d] = f2b(v[i]);        // k-norm already in ctx
        }
    }
    __syncthreads();
    short8 a0 = *(const short8*)(ctxT + l31 * 40 + l5 * 8);
    short8 a1 = *(const short8*)(ctxT + l31 * 40 + 16 + l5 * 8);

    const ushort_t* qbase = qkv + (size_t)(h * 32) * NCOLS;
    int segbase = b * NTOK + sl * 512;
    int d = tid & 31, t8 = (tid >> 5) * 8;
    float ssum = 0.f;
#pragma unroll
    for (int s = 0; s < 8; s++) ssum += qpart[((size_t)s * 128 + bh) * 32 + d];
    float sq = 1.f / ssum;                       // per-thread row scale

    for (int nc = 0; nc < 2; nc++) {
        int gcol0 = segbase + nc * 256;
#pragma unroll
        for (int jj = 0; jj < 4; jj++) {
            int tok8 = jj * 64 + t8;
            short8 pk = *(const short8*)(qbase + (size_t)d * NCOLS + gcol0 + tok8);
#pragma unroll
            for (int j = 0; j < 8; j++)
                qT[(tok8 + j) * 40 + d] = f2b(__expf(b2f((ushort_t)pk[j])) * sq);
        }
        __syncthreads();
#pragma unroll
        for (int ti = 0; ti < 2; ti++) {
            int tok0 = (wave + ti * 4) * 32;
            f32x16 acc;
#pragma unroll
            for (int i = 0; i < 16; i++) acc[i] = 0.f;
            short8 b0 = *(const short8*)(qT + (size_t)(tok0 + l31) * 40 + l5 * 8);
            short8 b1 = *(const short8*)(qT + (size_t)(tok0 + l31) * 40 + 16 + l5 * 8);
            acc = __builtin_amdgcn_mfma_f32_32x32x16_bf16(a0, b0, acc, 0, 0, 0);
            acc = __builtin_amdgcn_mfma_f32_32x32x16_bf16(a1, b1, acc, 0, 0, 0);
#pragma unroll
            for (int r = 0; r < 16; r++) {
                int e = (r & 3) + 8 * (r >> 2) + 4 * l5;
                obuf[wave][l31 * 40 + e] = f2b(acc[r]);
            }
            {
                int tok = lane >> 1, half = lane & 1;
                const ushort_t* srcp = &obuf[wave][tok * 40 + half * 16];
                short8 r0 = *(const short8*)srcp;
                short8 r1 = *(const short8*)(srcp + 8);
                size_t g = (size_t)(gcol0 + tok0 + tok) * 256 + h * 32 + half * 16;
                *(short8*)(attT + g) = r0;
                *(short8*)(attT + g + 8) = r1;
            }
        }
        __syncthreads();
    }
}

// ---------------------------------------------------------------------------
extern "C" void kernel_launch(void* const* d_in, const int* in_sizes, int n_in,
                              void* d_out, int out_size, void* d_ws, size_t ws_size,
                              hipStream_t stream) {
    const float* x          = (const float*)d_in[0];
    const float* qkv_w      = (const float*)d_in[1];
    const float* qkv_gamma  = (const float*)d_in[2];
    const float* qkv_beta   = (const float*)d_in[3];
    const float* qkv_mean   = (const float*)d_in[4];
    const float* qkv_var    = (const float*)d_in[5];
    const float* proj_w     = (const float*)d_in[6];
    const float* proj_gamma = (const float*)d_in[7];
    const float* proj_beta  = (const float*)d_in[8];
    const float* proj_mean  = (const float*)d_in[9];
    const float* proj_var   = (const float*)d_in[10];

    ushort_t* wqb = (ushort_t*)d_ws;                 // 393,216 B
    ushort_t* wpb = wqb + 768 * 256;                 // 131,072 B
    ushort_t* xt  = wpb + 256 * 256;                 // 33.5 MB (also attT later)
    ushort_t* qkv = xt + (size_t)NCOLS * CIN;        // 100.7 MB
    float* out     = (float*)d_out;
    float* ctxpart = (float*)d_out;                  // 4 MB scratch in d_out
    float* qpart   = ctxpart + 8 * 128 * 1024;       // 128 KB scratch

    prep_x<<<1024, 256, 0, stream>>>(x, xt, qkv_w, proj_w, wqb, wpb);
    gemm128<<<3072, 256, 0, stream>>>(wqb, xt, qkv_gamma, qkv_beta,
                                      qkv_mean, qkv_var, qkv, nullptr, 6, 0);
    ctx_ker<<<dim3(8, 128), 256, 0, stream>>>(qkv, ctxpart, qpart);
    out_ker<<<dim3(8, 128), 256, 0, stream>>>(qkv, ctxpart, qpart, xt);
    gemm128<<<1024, 256, 0, stream>>>(wpb, xt, proj_gamma, proj_beta,
                                      proj_mean, proj_var, nullptr, out, 2, 1);
}

// Round 10
// 261.300 us; speedup vs baseline: 1.4717x; 1.0083x over previous
//
#include <hip/hip_runtime.h>

typedef unsigned short ushort_t;
typedef unsigned int u32;
typedef short short8 __attribute__((ext_vector_type(8)));
typedef float f32x4 __attribute__((ext_vector_type(4)));
typedef float f32x16 __attribute__((ext_vector_type(16)));

#define NTOK 4096
#define NCOLS 65536
#define CIN 256

__device__ __forceinline__ float b2f(ushort_t u) {
    union { unsigned int i; float f; } v; v.i = ((unsigned int)u) << 16; return v.f;
}
__device__ __forceinline__ ushort_t f2b(float f) {
    union { float f; unsigned int i; } v; v.f = f;
    unsigned int r = v.i + 0x7FFFu + ((v.i >> 16) & 1u);   // RNE
    return (ushort_t)(r >> 16);
}

__device__ __forceinline__ void gl_lds16(const ushort_t* g, ushort_t* l) {
    __builtin_amdgcn_global_load_lds(
        (const __attribute__((address_space(1))) u32*)(const void*)g,
        (__attribute__((address_space(3))) u32*)(void*)l,
        16, 0, 0);
}

// ---------------------------------------------------------------------------
// prep: x fp32 [16][256][4096] -> xt bf16 [65536][256]  (LDS-tiled transpose)
//       + weights fp32->bf16 (folded cvt_w)
// R10: x loads vectorized to float4 (G13) — 16 loads/thread (1 KB/wave-inst)
// instead of 64 scalar 4B loads; LDS writes 4-way (was 8-way) conflict.
__global__ __launch_bounds__(256) void prep_x(const float* __restrict__ x,
                                              ushort_t* __restrict__ xt,
                                              const float* __restrict__ wq,
                                              const float* __restrict__ wp,
                                              ushort_t* __restrict__ wqb,
                                              ushort_t* __restrict__ wpb) {
    __shared__ ushort_t lds[64 * 264];           // 33,792 B; 528B rows (16B-aligned)
    int tid = threadIdx.x;

    // folded cvt_w: 1 weight elem per thread
    int i = blockIdx.x * 256 + tid;              // 0 .. 262143
    if (i < 768 * 256) wqb[i] = f2b(wq[i]);
    else               wpb[i - 768 * 256] = f2b(wp[i - 768 * 256]);

    int g0 = blockIdx.x * 64;                    // 64 tokens per block
    int b = g0 >> 12, n0 = g0 & 4095;
    const float* src = x + (size_t)b * (CIN * NTOK) + n0;
    int t4 = (tid & 15) * 4;                     // this lane's 4 tokens
    int crow = tid >> 4;                         // 0..15 channel sub-row
    for (int cr = 0; cr < 16; cr++) {
        int c = cr * 16 + crow;
        f32x4 v = *(const f32x4*)(src + (size_t)c * NTOK + t4);
#pragma unroll
        for (int j = 0; j < 4; j++)
            lds[(t4 + j) * 264 + c] = f2b(v[j]);
    }
    __syncthreads();
    int tok = tid >> 2, c8 = (tid & 3) * 8;
    ushort_t* dst = xt + (size_t)(g0 + tok) * CIN + c8;
#pragma unroll
    for (int j = 0; j < 8; j++)
        *(short8*)(dst + j * 32) = *(const short8*)&lds[tok * 264 + c8 + j * 32];
}

// ---------------------------------------------------------------------------
// R1-proven 128x128-tile GEMM + thin BN epilogue + T1 XCD swizzle (R8, -7.6µs).
// (R9 note: LDS XOR swizzle was a bank no-op — removed; the 3.1M conflict
// count is the intrinsic b128 wave-serialization floor, not fixable here.)
// mode 0: out_b[m*65536 + col] bf16   |   mode 1: out_f[b][m][n] fp32
__global__ __launch_bounds__(256) void gemm128(const ushort_t* __restrict__ W,
                                               const ushort_t* __restrict__ Xc,
                                               const float* __restrict__ gamma,
                                               const float* __restrict__ beta,
                                               const float* __restrict__ mean,
                                               const float* __restrict__ var,
                                               ushort_t* __restrict__ out_b,
                                               float* __restrict__ out_f,
                                               int mtiles, int mode) {
    __shared__ __align__(16) ushort_t lA[128 * 32];
    __shared__ __align__(16) ushort_t lB[128 * 32];
    int tid = threadIdx.x;
    int wave = tid >> 6, lane = tid & 63;
    int l15 = lane & 15, q = lane >> 4;
    int mh = wave >> 1, nh = wave & 1;

    // XCD swizzle: cpx = nwg/8 = mtiles*64; bijective since nwg%8==0
    int bid = blockIdx.x;
    int swz = (bid & 7) * (mtiles * 64) + (bid >> 3);
    int m0 = (swz % mtiles) * 128, colb = (swz / mtiles) * 128;

    f32x4 acc[4][4];
#pragma unroll
    for (int i = 0; i < 4; i++)
#pragma unroll
        for (int j = 0; j < 4; j++)
#pragma unroll
            for (int r = 0; r < 4; r++) acc[i][j][r] = 0.f;

    const ushort_t* gA0 = W  + (size_t)(m0 +      (tid >> 2)) * CIN + (tid & 3) * 8;
    const ushort_t* gA1 = W  + (size_t)(m0 + 64 + (tid >> 2)) * CIN + (tid & 3) * 8;
    const ushort_t* gB0 = Xc + (size_t)(colb +      (tid >> 2)) * CIN + (tid & 3) * 8;
    const ushort_t* gB1 = Xc + (size_t)(colb + 64 + (tid >> 2)) * CIN + (tid & 3) * 8;
    ushort_t* la0 = &lA[tid * 8];
    ushort_t* la1 = &lA[2048 + tid * 8];
    ushort_t* lb0 = &lB[tid * 8];
    ushort_t* lb1 = &lB[2048 + tid * 8];

    for (int k0 = 0; k0 < CIN; k0 += 32) {
        gl_lds16(gA0 + k0, la0);
        gl_lds16(gA1 + k0, la1);
        gl_lds16(gB0 + k0, lb0);
        gl_lds16(gB1 + k0, lb1);
        __syncthreads();
        short8 af[4], bf[4];
#pragma unroll
        for (int i = 0; i < 4; i++) {
            af[i] = *(const short8*)&lA[(mh * 64 + i * 16 + l15) * 32 + q * 8];
            bf[i] = *(const short8*)&lB[(nh * 64 + i * 16 + l15) * 32 + q * 8];
        }
#pragma unroll
        for (int mi = 0; mi < 4; mi++)
#pragma unroll
            for (int ni = 0; ni < 4; ni++)
                acc[mi][ni] = __builtin_amdgcn_mfma_f32_16x16x32_bf16(af[mi], bf[ni],
                                                                      acc[mi][ni], 0, 0, 0);
        __syncthreads();
    }

    int col_l = colb + nh * 64 + l15;
#pragma unroll
    for (int mi = 0; mi < 4; mi++) {
#pragma unroll
        for (int r = 0; r < 4; r++) {
            int m = m0 + mh * 64 + mi * 16 + q * 4 + r;
            float sc = gamma[m] * rsqrtf(var[m] + 1e-5f);
            float sh = beta[m] - mean[m] * sc;
#pragma unroll
            for (int ni = 0; ni < 4; ni++) {
                float val = acc[mi][ni][r] * sc + sh;
                int col = col_l + ni * 16;
                if (mode == 0) {
                    out_b[(size_t)m * NCOLS + col] = f2b(val);
                } else {
                    int bb = col >> 12, n = col & 4095;
                    out_f[(size_t)bb * (CIN * NTOK) + (size_t)m * NTOK + n] = val;
                }
            }
        }
    }
}

// ---------------------------------------------------------------------------
// ctx kernel with fused denominators (sum_ker eliminated):
//  pre-pass A: rsm[tok] = 1/sum_d exp(k[d][tok])  (d-ascending — bitwise ==
//              old sum_ker order; block-local 512 tokens, coalesced u32 loads)
//  pre-pass B: qpart[sl][bh][ch] = sum over this sl's 512 tokens of exp(q)
//              (out_ker sums the 8 partials — no atomics)
//  main: ctxpart[sl][bh][d][e] = sum_n (exp(k[d][n])*rsm[n]) * v[e][n]
__global__ __launch_bounds__(256) void ctx_ker(const ushort_t* __restrict__ qkv,
                                               float* __restrict__ ctxpart,
                                               float* __restrict__ qpart) {
    int sl = blockIdx.x, bh = blockIdx.y;
    int b = bh >> 3, h = bh & 7;
    int tid = threadIdx.x, wave = tid >> 6, lane = tid & 63;
    int l31 = lane & 31, l5 = lane >> 5;
    int colbase = b * NTOK + sl * 512;

    __shared__ float rsm[512];
    __shared__ float red2[256];

    {   // pre-pass A: per-token k-denominator (2 tokens/thread, u32 loads)
        const ushort_t* kb = qkv + (size_t)(256 + h * 32) * NCOLS + colbase + tid * 2;
        float s0 = 0.f, s1 = 0.f;
#pragma unroll
        for (int d = 0; d < 32; d++) {
            u32 w = *(const u32*)(kb + (size_t)d * NCOLS);
            s0 += __expf(b2f((ushort_t)(w & 0xffffu)));
            s1 += __expf(b2f((ushort_t)(w >> 16)));
        }
        rsm[tid * 2]     = 1.f / s0;
        rsm[tid * 2 + 1] = 1.f / s1;
    }
    {   // pre-pass B: q partial sums (thread = (ch, 64-token slot))
        int ch = tid >> 3, slot = tid & 7;
        const ushort_t* qb = qkv + (size_t)(h * 32 + ch) * NCOLS + colbase + slot * 64;
        float s = 0.f;
#pragma unroll
        for (int j = 0; j < 8; j++) {
            short8 pk = *(const short8*)(qb + j * 8);
#pragma unroll
            for (int i = 0; i < 8; i++) s += __expf(b2f((ushort_t)pk[i]));
        }
        red2[tid] = s;
    }
    __syncthreads();
    if (tid < 32) {
        float ss = 0.f;
#pragma unroll
        for (int k = 0; k < 8; k++) ss += red2[tid * 8 + k];
        qpart[((size_t)sl * 128 + bh) * 32 + tid] = ss;
    }

    int col0 = colbase + wave * 128;
    const ushort_t* krow = qkv + (size_t)(256 + h * 32 + l31) * NCOLS + col0 + l5 * 8;
    const ushort_t* vrow = qkv + (size_t)(512 + h * 32 + l31) * NCOLS + col0 + l5 * 8;
    int rbase = wave * 128 + l5 * 8;
    f32x16 acc;
#pragma unroll
    for (int i = 0; i < 16; i++) acc[i] = 0.f;
#pragma unroll
    for (int st = 0; st < 8; st++) {
        short8 kf = *(const short8*)(krow + st * 16);
        short8 vf = *(const short8*)(vrow + st * 16);   // v raw (B operand)
        f32x4 ra = *(const f32x4*)&rsm[rbase + st * 16];
        f32x4 rb = *(const f32x4*)&rsm[rbase + st * 16 + 4];
        short8 af;
#pragma unroll
        for (int j = 0; j < 4; j++)
            af[j] = (short)f2b(__expf(b2f((ushort_t)kf[j])) * ra[j]);
#pragma unroll
        for (int j = 0; j < 4; j++)
            af[j + 4] = (short)f2b(__expf(b2f((ushort_t)kf[j + 4])) * rb[j]);
        acc = __builtin_amdgcn_mfma_f32_32x32x16_bf16(af, vf, acc, 0, 0, 0);
    }
    __shared__ float red[4][1024];
#pragma unroll
    for (int r = 0; r < 16; r++) {
        int d = (r & 3) + 8 * (r >> 2) + 4 * l5;        // C/D row (m74/m101)
        red[wave][d * 32 + l31] = acc[r];
    }
    __syncthreads();
    int i0 = tid * 4;
    f32x4 vv;
#pragma unroll
    for (int i = 0; i < 4; i++)
        vv[i] = red[0][i0 + i] + red[1][i0 + i] + red[2][i0 + i] + red[3][i0 + i];
    *(f32x4*)(ctxpart + ((size_t)sl * 128 + bh) * 1024 + i0) = vv;
}

// ---------------------------------------------------------------------------
// out[e][n] = sum_d ctx[d][e] * (exp(q[d][n])/S_q[d])  -> attT[token][256]
// ctx = sum of 8 ctxpart slices; S_q = sum of 8 qpart slices (no atomics).
__global__ __launch_bounds__(256) void out_ker(const ushort_t* __restrict__ qkv,
                                               const float* __restrict__ ctxpart,
                                               const float* __restrict__ qpart,
                                               ushort_t* __restrict__ attT) {
    int sl = blockIdx.x, bh = blockIdx.y;
    int b = bh >> 3, h = bh & 7;
    int tid = threadIdx.x, wave = tid >> 6, lane = tid & 63;
    int l31 = lane & 31, l5 = lane >> 5;
    __shared__ __align__(16) ushort_t ctxT[32 * 40];
    __shared__ __align__(16) ushort_t qT[256 * 40];
    __shared__ __align__(16) ushort_t obuf[4][32 * 40];

    {
        int i0 = tid * 4;
        f32x4 v;
#pragma unroll
        for (int i = 0; i < 4; i++) v[i] = 0.f;
#pragma unroll
        for (int s = 0; s < 8; s++)
            v += *(const f32x4*)(ctxpart + ((size_t)s * 128 + bh) * 1024 + i0);
#pragma unroll
        for (int i = 0; i < 4; i++) {
            int idx = i0 + i;
            int d = idx >> 5, e = idx & 31;
            ctxT[e * 40 + d] = f2b(v[i]);        // k-norm already in ctx
        }
    }
    __syncthreads();
    short8 a0 = *(const short8*)(ctxT + l31 * 40 + l5 * 8);
    short8 a1 = *(const short8*)(ctxT + l31 * 40 + 16 + l5 * 8);

    const ushort_t* qbase = qkv + (size_t)(h * 32) * NCOLS;
    int segbase = b * NTOK + sl * 512;
    int d = tid & 31, t8 = (tid >> 5) * 8;
    float ssum = 0.f;
#pragma unroll
    for (int s = 0; s < 8; s++) ssum += qpart[((size_t)s * 128 + bh) * 32 + d];
    float sq = 1.f / ssum;                       // per-thread row scale

    for (int nc = 0; nc < 2; nc++) {
        int gcol0 = segbase + nc * 256;
#pragma unroll
        for (int jj = 0; jj < 4; jj++) {
            int tok8 = jj * 64 + t8;
            short8 pk = *(const short8*)(qbase + (size_t)d * NCOLS + gcol0 + tok8);
#pragma unroll
            for (int j = 0; j < 8; j++)
                qT[(tok8 + j) * 40 + d] = f2b(__expf(b2f((ushort_t)pk[j])) * sq);
        }
        __syncthreads();
#pragma unroll
        for (int ti = 0; ti < 2; ti++) {
            int tok0 = (wave + ti * 4) * 32;
            f32x16 acc;
#pragma unroll
            for (int i = 0; i < 16; i++) acc[i] = 0.f;
            short8 b0 = *(const short8*)(qT + (size_t)(tok0 + l31) * 40 + l5 * 8);
            short8 b1 = *(const short8*)(qT + (size_t)(tok0 + l31) * 40 + 16 + l5 * 8);
            acc = __builtin_amdgcn_mfma_f32_32x32x16_bf16(a0, b0, acc, 0, 0, 0);
            acc = __builtin_amdgcn_mfma_f32_32x32x16_bf16(a1, b1, acc, 0, 0, 0);
#pragma unroll
            for (int r = 0; r < 16; r++) {
                int e = (r & 3) + 8 * (r >> 2) + 4 * l5;
                obuf[wave][l31 * 40 + e] = f2b(acc[r]);
            }
            {
                int tok = lane >> 1, half = lane & 1;
                const ushort_t* srcp = &obuf[wave][tok * 40 + half * 16];
                short8 r0 = *(const short8*)srcp;
                short8 r1 = *(const short8*)(srcp + 8);
                size_t g = (size_t)(gcol0 + tok0 + tok) * 256 + h * 32 + half * 16;
                *(short8*)(attT + g) = r0;
                *(short8*)(attT + g + 8) = r1;
            }
        }
        __syncthreads();
    }
}

// ---------------------------------------------------------------------------
extern "C" void kernel_launch(void* const* d_in, const int* in_sizes, int n_in,
                              void* d_out, int out_size, void* d_ws, size_t ws_size,
                              hipStream_t stream) {
    const float* x          = (const float*)d_in[0];
    const float* qkv_w      = (const float*)d_in[1];
    const float* qkv_gamma  = (const float*)d_in[2];
    const float* qkv_beta   = (const float*)d_in[3];
    const float* qkv_mean   = (const float*)d_in[4];
    const float* qkv_var    = (const float*)d_in[5];
    const float* proj_w     = (const float*)d_in[6];
    const float* proj_gamma = (const float*)d_in[7];
    const float* proj_beta  = (const float*)d_in[8];
    const float* proj_mean  = (const float*)d_in[9];
    const float* proj_var   = (const float*)d_in[10];

    ushort_t* wqb = (ushort_t*)d_ws;                 // 393,216 B
    ushort_t* wpb = wqb + 768 * 256;                 // 131,072 B
    ushort_t* xt  = wpb + 256 * 256;                 // 33.5 MB (also attT later)
    ushort_t* qkv = xt + (size_t)NCOLS * CIN;        // 100.7 MB
    float* out     = (float*)d_out;
    float* ctxpart = (float*)d_out;                  // 4 MB scratch in d_out
    float* qpart   = ctxpart + 8 * 128 * 1024;       // 128 KB scratch

    prep_x<<<1024, 256, 0, stream>>>(x, xt, qkv_w, proj_w, wqb, wpb);
    gemm128<<<3072, 256, 0, stream>>>(wqb, xt, qkv_gamma, qkv_beta,
                                      qkv_mean, qkv_var, qkv, nullptr, 6, 0);
    ctx_ker<<<dim3(8, 128), 256, 0, stream>>>(qkv, ctxpart, qpart);
    out_ker<<<dim3(8, 128), 256, 0, stream>>>(qkv, ctxpart, qpart, xt);
    gemm128<<<1024, 256, 0, stream>>>(wpb, xt, proj_gamma, proj_beta,
                                      proj_mean, proj_var, nullptr, out, 2, 1);
}